// Round 3
// baseline (7050.538 us; speedup 1.0000x reference)
//
#include <hip/hip_runtime.h>
#include <cmath>

// ---------------------------------------------------------------------------
// BiDirectionalAddFFBlock: LN -> mamba(fwd)+mamba(rev) -> gelu residual ->
// LN -> FFN.  B=4, L=2048, D=1024, di=2048, ds=16, dt_rank=64, DFF=4096.
// Round 2: adaptive workspace (ws_size turned out < 156MB -> round-1 guard
// fired).  d_out doubles as the f32 fwd+bwd accumulator; fp32->bf16 weight
// convert fused into GEMM staging; L segmented (nseg picked from ws_size)
// with scan-state carry + conv halo.  bf16 MFMA GEMMs throughout.
// ---------------------------------------------------------------------------

namespace {

using u16 = unsigned short;

constexpr int kB = 4;
constexpr int kL = 2048;
constexpr int kD = 1024;
constexpr int kDI = 2048;
constexpr int kDFF = 4096;
constexpr int kDS = 16;
constexpr int kDtRank = 64;
constexpr int kNPad = 128;       // x_proj N=96 padded to 128
constexpr int kM = kB * kL;      // 8192 rows

typedef short bf16x8 __attribute__((ext_vector_type(8)));
typedef float f32x4  __attribute__((ext_vector_type(4)));

__device__ __forceinline__ float bf2f(u16 u) {
  union { unsigned int i; float f; } c; c.i = ((unsigned int)u) << 16; return c.f;
}
__device__ __forceinline__ u16 f2bf(float f) {  // round-to-nearest-even
  union { float f; unsigned int i; } c; c.f = f;
  return (u16)((c.i + 0x7FFFu + ((c.i >> 16) & 1u)) >> 16);
}
__device__ __forceinline__ float geluf(float v) {
  return 0.5f * v * (1.f + erff(v * 0.70710678118654752f));
}
__device__ __forceinline__ float softplusf(float v) {
  return (v > 0.f) ? (v + log1pf(__expf(-v))) : log1pf(__expf(v));
}
__device__ __forceinline__ float siluf(float v) {
  return v / (1.f + __expf(-v));
}

// ---------------------------------------------------------------------------
// LayerNorm fp32 row (1024) -> bf16.  One block per row.
// ---------------------------------------------------------------------------
__global__ __launch_bounds__(256) void ln_kernel(
    const float* __restrict__ x, const float* __restrict__ g,
    const float* __restrict__ b, u16* __restrict__ out) {
  const int row = blockIdx.x;
  const int tid = threadIdx.x;
  const float4 v = ((const float4*)(x + (size_t)row * kD))[tid];
  float s  = v.x + v.y + v.z + v.w;
  float ss = v.x * v.x + v.y * v.y + v.z * v.z + v.w * v.w;
  #pragma unroll
  for (int off = 32; off; off >>= 1) {
    s  += __shfl_xor(s, off);
    ss += __shfl_xor(ss, off);
  }
  __shared__ float ls[4], lss[4];
  const int wid = tid >> 6;
  if ((tid & 63) == 0) { ls[wid] = s; lss[wid] = ss; }
  __syncthreads();
  s  = ls[0] + ls[1] + ls[2] + ls[3];
  ss = lss[0] + lss[1] + lss[2] + lss[3];
  const float mu  = s * (1.f / kD);
  const float inv = rsqrtf(ss * (1.f / kD) - mu * mu + 1e-5f);
  const float4 gg = ((const float4*)g)[tid];
  const float4 bb = ((const float4*)b)[tid];
  ushort4 o;
  o.x = f2bf((v.x - mu) * inv * gg.x + bb.x);
  o.y = f2bf((v.y - mu) * inv * gg.y + bb.y);
  o.z = f2bf((v.z - mu) * inv * gg.z + bb.z);
  o.w = f2bf((v.w - mu) * inv * gg.w + bb.w);
  ((ushort4*)(out + (size_t)row * kD))[tid] = o;
}

// ---------------------------------------------------------------------------
// bf16 MFMA GEMM: C[M,N] = A[M,K] * W[N,K]^T  (+bias)(+gelu)(+=C)
// 128x128 tile, BK=64, 4 waves (2x2), wave does 64x64 via 16x16x32 MFMA.
// Frags (guide §3, m89-verified): A[m=lane&15][k=quad*8+j]; B likewise on
// W[n][k]; C/D col=lane&15, row=quad*4+reg.
// AMAP: A row = b*kL + (REV ? kL-1-row_off-ll : row_off+ll), segment-compact
//       rows r: b=r/seg_len, ll=r%seg_len (seg_len % 128 == 0 so per-tile
//       uniform).  CMAP: same (never reversed).  Identity otherwise.
// WF32: W is fp32, converted to bf16 during LDS staging; rows >= wrows -> 0.
// ---------------------------------------------------------------------------
template <int ACT, bool BIAS, bool ACC, bool OUTBF, bool REV, bool WF32,
          bool AMAP, bool CMAP>
__global__ __launch_bounds__(256) void gemm_mfma(
    const u16* __restrict__ A, int lda,
    const void* __restrict__ W, int ldw, int wrows,
    void* __restrict__ Cp, int ldc, int K,
    const float* __restrict__ bias, int seg_len, int row_off) {
  __shared__ __align__(16) u16 As[128][72];
  __shared__ __align__(16) u16 Ws[128][72];
  const int tid  = threadIdx.x;
  const int bm   = blockIdx.x * 128;
  const int bn   = blockIdx.y * 128;
  const int lane = tid & 63;
  const int wave = tid >> 6;
  const int wm   = (wave >> 1) * 64;
  const int wn   = (wave & 1) * 64;
  const int l15  = lane & 15;
  const int quad = lane >> 4;
  const int lrow = tid >> 3;        // 0..31
  const int lcol = (tid & 7) * 8;   // 0..56

  // per-tile segment decomposition (b, ll0 uniform across the 128-row tile)
  int ab = 0, all0 = bm;
  if (AMAP || CMAP) {
    ab = bm / seg_len;
    all0 = bm - ab * seg_len;
  }

  f32x4 acc[4][4];
  #pragma unroll
  for (int i = 0; i < 4; i++)
    #pragma unroll
    for (int j = 0; j < 4; j++) acc[i][j] = (f32x4){0.f, 0.f, 0.f, 0.f};

  for (int k0 = 0; k0 < K; k0 += 64) {
    #pragma unroll
    for (int it = 0; it < 4; it++) {
      const int rl = it * 32 + lrow;
      int arow;
      if (AMAP) {
        arow = REV ? (ab * kL + kL - 1 - row_off - all0 - rl)
                   : (ab * kL + row_off + all0 + rl);
      } else {
        arow = bm + rl;
      }
      *(int4*)&As[rl][lcol] = *(const int4*)(A + (size_t)arow * lda + k0 + lcol);

      const int rn = bn + rl;
      if (WF32) {
        union { ushort u[8]; int4 v; } pk;
        if (rn < wrows) {
          const float* wp = (const float*)W + (size_t)rn * ldw + k0 + lcol;
          const float4 p = *(const float4*)wp;
          const float4 q = *(const float4*)(wp + 4);
          pk.u[0] = f2bf(p.x); pk.u[1] = f2bf(p.y);
          pk.u[2] = f2bf(p.z); pk.u[3] = f2bf(p.w);
          pk.u[4] = f2bf(q.x); pk.u[5] = f2bf(q.y);
          pk.u[6] = f2bf(q.z); pk.u[7] = f2bf(q.w);
        } else {
          pk.v = (int4){0, 0, 0, 0};
        }
        *(int4*)&Ws[rl][lcol] = pk.v;
      } else {
        *(int4*)&Ws[rl][lcol] =
            *(const int4*)((const u16*)W + (size_t)rn * ldw + k0 + lcol);
      }
    }
    __syncthreads();
    #pragma unroll
    for (int ks = 0; ks < 64; ks += 32) {
      bf16x8 af[4], wf[4];
      #pragma unroll
      for (int i = 0; i < 4; i++)
        af[i] = *(const bf16x8*)&As[wm + i * 16 + l15][ks + quad * 8];
      #pragma unroll
      for (int j = 0; j < 4; j++)
        wf[j] = *(const bf16x8*)&Ws[wn + j * 16 + l15][ks + quad * 8];
      #pragma unroll
      for (int i = 0; i < 4; i++)
        #pragma unroll
        for (int j = 0; j < 4; j++)
          acc[i][j] = __builtin_amdgcn_mfma_f32_16x16x32_bf16(
              af[i], wf[j], acc[i][j], 0, 0, 0);
    }
    __syncthreads();
  }

  #pragma unroll
  for (int i = 0; i < 4; i++) {
    #pragma unroll
    for (int j = 0; j < 4; j++) {
      const int col = bn + wn + j * 16 + l15;
      #pragma unroll
      for (int r = 0; r < 4; r++) {
        const int rl2 = wm + i * 16 + quad * 4 + r;
        const int crow = CMAP ? (ab * kL + row_off + all0 + rl2) : (bm + rl2);
        float v = acc[i][j][r];
        if (BIAS) v += bias[col];
        if (ACT == 2) v = geluf(v);
        if (OUTBF) {
          ((u16*)Cp)[(size_t)crow * ldc + col] = f2bf(v);
        } else {
          float* p = (float*)Cp + (size_t)crow * ldc + col;
          if (ACC) *p = *p + v; else *p = v;
        }
      }
    }
  }
}

// ---------------------------------------------------------------------------
// Causal depthwise conv (k=4) + bias + silu on one segment (compact rows).
// xz: [Mseg, 4096] bf16 (x in cols 0..2047).  Halo: tail_in = last 3 rows of
// previous segment per batch; threads in last 3 rows write tail_out.
// ---------------------------------------------------------------------------
__global__ __launch_bounds__(256) void conv_silu_kernel(
    const u16* __restrict__ xz, const float* __restrict__ w,
    const float* __restrict__ cb, u16* __restrict__ xs,
    const u16* __restrict__ tail_in, u16* __restrict__ tail_out,
    int seg_len, int row_off) {
  const int t = blockIdx.x * 256 + threadIdx.x;  // Mseg*kDI threads
  const int c = t & (kDI - 1);
  const int r = t >> 11;              // compact row
  const int b = r / seg_len;
  const int ll = r - b * seg_len;
  const int tpos = row_off + ll;      // processing-order position in [0,L)

  const float xv0 = bf2f(xz[(size_t)r * (2 * kDI) + c]);
  float acc = cb[c] + w[c * 4 + 3] * xv0;
  #pragma unroll
  for (int j = 1; j <= 3; j++) {
    if (tpos - j >= 0) {
      float xp;
      if (ll - j >= 0) {
        xp = bf2f(xz[(size_t)(r - j) * (2 * kDI) + c]);
      } else {
        // slot 2 = pos row_off-1, 1 = row_off-2, 0 = row_off-3
        xp = bf2f(tail_in[(b * 3 + (3 + ll - j)) * kDI + c]);
      }
      acc += w[c * 4 + 3 - j] * xp;
    }
  }
  xs[(size_t)r * kDI + c] = f2bf(siluf(acc));
  if (ll >= seg_len - 3) {
    tail_out[(b * 3 + (ll - (seg_len - 3))) * kDI + c] = f2bf(xv0);
  }
}

// ---------------------------------------------------------------------------
// Selective scan over one segment with fused dt_proj+softplus.
// Lane = (b, c, s); 16 state lanes per channel; shfl width 16.
// State carried in hstate (f32) across segments.  y overwrites xs.
// ---------------------------------------------------------------------------
__global__ __launch_bounds__(256) void scan_kernel(
    const float* __restrict__ dbl, const u16* __restrict__ xz,
    const float* __restrict__ dt_w, const float* __restrict__ dt_b,
    const float* __restrict__ Alog, const float* __restrict__ Dp,
    u16* __restrict__ xs, float* __restrict__ hstate,
    int seg_len, int first) {
  const int t = blockIdx.x * 256 + threadIdx.x;  // B*DI*16
  const int s = t & 15;
  const int c = (t >> 4) & (kDI - 1);
  const int b = t >> 15;
  const float Av  = -__expf(Alog[c * kDS + s]);
  const float Dv  = Dp[c];
  const float dtb = dt_b[c];
  const float4 w4 = *(const float4*)(dt_w + c * kDtRank + s * 4);
  float h = 0.f;
  if (!first) h = hstate[t];
  for (int ll = 0; ll < seg_len; ll++) {
    const size_t row = (size_t)b * seg_len + ll;
    const float4 d4 = *(const float4*)(dbl + row * kNPad + s * 4);
    float dtp = d4.x * w4.x + d4.y * w4.y + d4.z * w4.z + d4.w * w4.w;
    dtp += __shfl_xor(dtp, 1, 16);
    dtp += __shfl_xor(dtp, 2, 16);
    dtp += __shfl_xor(dtp, 4, 16);
    dtp += __shfl_xor(dtp, 8, 16);
    const float dtv = softplusf(dtp + dtb);
    const float xv  = bf2f(xs[row * kDI + c]);
    const float Bv  = dbl[row * kNPad + kDtRank + s];
    const float Cv  = dbl[row * kNPad + kDtRank + kDS + s];
    h = __expf(dtv * Av) * h + dtv * Bv * xv;
    float p = h * Cv;
    p += __shfl_xor(p, 1, 16);
    p += __shfl_xor(p, 2, 16);
    p += __shfl_xor(p, 4, 16);
    p += __shfl_xor(p, 8, 16);
    if (s == 0) {
      const float z = bf2f(xz[row * (2 * kDI) + kDI + c]);
      xs[row * kDI + c] = f2bf((p + Dv * xv) * siluf(z));
    }
  }
  hstate[t] = h;
}

// out = x + gelu(out + x)  in place (out currently holds fwd+bwd, f32)
__global__ __launch_bounds__(256) void combine_kernel(
    const float* __restrict__ x, float* __restrict__ out) {
  const size_t i = (size_t)blockIdx.x * 256 + threadIdx.x;  // M*D/4
  const float4 xv = ((const float4*)x)[i];
  const float4 bv = ((const float4*)out)[i];
  float4 o;
  o.x = xv.x + geluf(bv.x + xv.x);
  o.y = xv.y + geluf(bv.y + xv.y);
  o.z = xv.z + geluf(bv.z + xv.z);
  o.w = xv.w + geluf(bv.w + xv.w);
  ((float4*)out)[i] = o;
}

}  // namespace

extern "C" void kernel_launch(void* const* d_in, const int* in_sizes, int n_in,
                              void* d_out, int out_size, void* d_ws,
                              size_t ws_size, hipStream_t stream) {
  const float* x = (const float*)d_in[0];
  const float* in_w[2]    = {(const float*)d_in[1],  (const float*)d_in[10]};
  const float* conv_w[2]  = {(const float*)d_in[2],  (const float*)d_in[11]};
  const float* conv_b[2]  = {(const float*)d_in[3],  (const float*)d_in[12]};
  const float* xproj_w[2] = {(const float*)d_in[4],  (const float*)d_in[13]};
  const float* dt_w[2]    = {(const float*)d_in[5],  (const float*)d_in[14]};
  const float* dt_b[2]    = {(const float*)d_in[6],  (const float*)d_in[15]};
  const float* Alog[2]    = {(const float*)d_in[7],  (const float*)d_in[16]};
  const float* Dp[2]      = {(const float*)d_in[8],  (const float*)d_in[17]};
  const float* out_w[2]   = {(const float*)d_in[9],  (const float*)d_in[18]};
  const float* norm_g = (const float*)d_in[19];
  const float* norm_b = (const float*)d_in[20];
  const float* ffn_g  = (const float*)d_in[21];
  const float* ffn_b  = (const float*)d_in[22];
  const float* ff1_w  = (const float*)d_in[23];
  const float* ff1_b  = (const float*)d_in[24];
  const float* ff2_w  = (const float*)d_in[25];
  const float* ff2_b  = (const float*)d_in[26];
  float* out = (float*)d_out;

  // --- adaptive workspace layout ---------------------------------------
  auto need = [](int nseg) -> size_t {
    const size_t mseg = (size_t)kM / nseg;
    size_t sz = 0;
    sz += (size_t)kM * kD * 2;        // h  bf16
    sz += mseg * 4096 * 2;            // xz bf16 (aliases FFN hidden)
    sz += mseg * 2048 * 2;            // xs bf16
    sz += mseg * 128 * 4;             // dbl f32
    sz += (size_t)kB * kDI * kDS * 4; // hstate f32
    sz += 2 * (size_t)kB * 3 * kDI * 2; // conv tail double buffer
    sz += 8 * 256;                    // alignment slack
    return sz;
  };
  int nseg = 1;
  while (nseg <= 16 && need(nseg) > ws_size) nseg *= 2;
  if (nseg > 16) return;  // even minimal layout doesn't fit: clean fail
  const int Lseg = kL / nseg;
  const int Mseg = kM / nseg;

  char* base = (char*)d_ws;
  size_t off = 0;
  auto alloc = [&](size_t bytes) {
    char* p = base + off;
    off = (off + bytes + 255) & ~(size_t)255;
    return p;
  };
  u16*   h      = (u16*)alloc((size_t)kM * kD * 2);
  u16*   xz     = (u16*)alloc((size_t)Mseg * 4096 * 2);
  u16*   xs     = (u16*)alloc((size_t)Mseg * 2048 * 2);
  float* dbl    = (float*)alloc((size_t)Mseg * 128 * 4);
  float* hstate = (float*)alloc((size_t)kB * kDI * kDS * 4);
  u16*   tail0  = (u16*)alloc((size_t)kB * 3 * kDI * 2);
  u16*   tail1  = (u16*)alloc((size_t)kB * 3 * kDI * 2);

  // LN(x) -> h (bf16)
  ln_kernel<<<kM, 256, 0, stream>>>(x, norm_g, norm_b, h);

  for (int m = 0; m < 2; m++) {
    for (int s = 0; s < nseg; s++) {
      const int l0 = s * Lseg;
      u16* tin  = (s & 1) ? tail0 : tail1;
      u16* tout = (s & 1) ? tail1 : tail0;
      // in_proj: h rows (REV for m=1) x in_w[4096,1024]^T -> xz [Mseg,4096]
      if (m == 0)
        gemm_mfma<0, false, false, true, false, true, true, false>
            <<<dim3(Mseg / 128, 4096 / 128), 256, 0, stream>>>(
                h, kD, in_w[m], kD, 4096, xz, 4096, kD, nullptr, Lseg, l0);
      else
        gemm_mfma<0, false, false, true, true, true, true, false>
            <<<dim3(Mseg / 128, 4096 / 128), 256, 0, stream>>>(
                h, kD, in_w[m], kD, 4096, xz, 4096, kD, nullptr, Lseg, l0);
      // causal depthwise conv + silu -> xs
      conv_silu_kernel<<<(Mseg * kDI) / 256, 256, 0, stream>>>(
          xz, conv_w[m], conv_b[m], xs, tin, tout, Lseg, l0);
      // x_proj: xs[Mseg,2048] x xproj[96->128,2048]^T -> dbl f32 [Mseg,128]
      gemm_mfma<0, false, false, false, false, true, false, false>
          <<<dim3(Mseg / 128, 1), 256, 0, stream>>>(
              xs, kDI, xproj_w[m], kDI, kDtRank + 2 * kDS, dbl, kNPad, kDI,
              nullptr, Lseg, l0);
      // selective scan (fused dt_proj+softplus); y overwrites xs
      scan_kernel<<<(kB * kDI * kDS) / 256, 256, 0, stream>>>(
          dbl, xz, dt_w[m], dt_b[m], Alog[m], Dp[m], xs, hstate, Lseg,
          (s == 0) ? 1 : 0);
      // out_proj -> d_out rows (f32); m=1 accumulates
      if (m == 0)
        gemm_mfma<0, false, false, false, false, true, false, true>
            <<<dim3(Mseg / 128, kD / 128), 256, 0, stream>>>(
                xs, kDI, out_w[m], kDI, kD, out, kD, kDI, nullptr, Lseg, l0);
      else
        gemm_mfma<0, false, true, false, false, true, false, true>
            <<<dim3(Mseg / 128, kD / 128), 256, 0, stream>>>(
                xs, kDI, out_w[m], kDI, kD, out, kD, kDI, nullptr, Lseg, l0);
    }
  }

  // x2 = x + gelu(fwd + bwd + x), in place on d_out
  combine_kernel<<<(kM * kD) / 1024, 256, 0, stream>>>(x, out);

  // FFN: LN(x2) -> h ; per M-segment: hidden = gelu(h@ff1^T+b1) (alias xz);
  // out += hidden@ff2^T + b2
  ln_kernel<<<kM, 256, 0, stream>>>(out, ffn_g, ffn_b, h);
  for (int s = 0; s < nseg; s++) {
    const int r0 = s * Mseg;
    gemm_mfma<2, true, false, true, false, true, true, false>
        <<<dim3(Mseg / 128, kDFF / 128), 256, 0, stream>>>(
            h, kD, ff1_w, kD, kDFF, xz, kDFF, kD, ff1_b, Mseg, r0);
    gemm_mfma<0, true, true, false, false, true, false, true>
        <<<dim3(Mseg / 128, kD / 128), 256, 0, stream>>>(
            xz, kDFF, ff2_w, kDFF, kD, out, kD, kDFF, ff2_b, Mseg, r0);
  }
}

// Round 4
// 2193.328 us; speedup vs baseline: 3.2145x; 3.2145x over previous
//
#include <hip/hip_runtime.h>
#include <cmath>

// ---------------------------------------------------------------------------
// BiDirectionalAddFFBlock: LN -> mamba(fwd)+mamba(rev) -> gelu residual ->
// LN -> FFN.  B=4, L=2048, D=1024, di=2048, ds=16, dt_rank=64, DFF=4096.
// Round 3: scan was 79% of runtime (2x2795us, shfl-tree serial chain).
// Round 4: dt_proj moved to MFMA GEMM; scan rebuilt as 3-phase chunked
// recurrence with 16 states in registers per thread (zero cross-lane ops).
// ---------------------------------------------------------------------------

namespace {

using u16 = unsigned short;

constexpr int kB = 4;
constexpr int kL = 2048;
constexpr int kD = 1024;
constexpr int kDI = 2048;
constexpr int kDFF = 4096;
constexpr int kDS = 16;
constexpr int kDtRank = 64;
constexpr int kNPad = 128;       // x_proj N=96 padded to 128
constexpr int kM = kB * kL;      // 8192 rows
constexpr int kNCH = 16;         // scan chunks per segment

typedef short bf16x8 __attribute__((ext_vector_type(8)));
typedef float f32x4  __attribute__((ext_vector_type(4)));

__device__ __forceinline__ float bf2f(u16 u) {
  union { unsigned int i; float f; } c; c.i = ((unsigned int)u) << 16; return c.f;
}
__device__ __forceinline__ u16 f2bf(float f) {  // round-to-nearest-even
  union { float f; unsigned int i; } c; c.f = f;
  return (u16)((c.i + 0x7FFFu + ((c.i >> 16) & 1u)) >> 16);
}
__device__ __forceinline__ float geluf(float v) {
  return 0.5f * v * (1.f + erff(v * 0.70710678118654752f));
}
__device__ __forceinline__ float softplusf(float v) {
  return (v > 0.f) ? (v + log1pf(__expf(-v))) : log1pf(__expf(v));
}
__device__ __forceinline__ float siluf(float v) {
  return v / (1.f + __expf(-v));
}

// ---------------------------------------------------------------------------
// LayerNorm fp32 row (1024) -> bf16.  One block per row.
// ---------------------------------------------------------------------------
__global__ __launch_bounds__(256) void ln_kernel(
    const float* __restrict__ x, const float* __restrict__ g,
    const float* __restrict__ b, u16* __restrict__ out) {
  const int row = blockIdx.x;
  const int tid = threadIdx.x;
  const float4 v = ((const float4*)(x + (size_t)row * kD))[tid];
  float s  = v.x + v.y + v.z + v.w;
  float ss = v.x * v.x + v.y * v.y + v.z * v.z + v.w * v.w;
  #pragma unroll
  for (int off = 32; off; off >>= 1) {
    s  += __shfl_xor(s, off);
    ss += __shfl_xor(ss, off);
  }
  __shared__ float ls[4], lss[4];
  const int wid = tid >> 6;
  if ((tid & 63) == 0) { ls[wid] = s; lss[wid] = ss; }
  __syncthreads();
  s  = ls[0] + ls[1] + ls[2] + ls[3];
  ss = lss[0] + lss[1] + lss[2] + lss[3];
  const float mu  = s * (1.f / kD);
  const float inv = rsqrtf(ss * (1.f / kD) - mu * mu + 1e-5f);
  const float4 gg = ((const float4*)g)[tid];
  const float4 bb = ((const float4*)b)[tid];
  ushort4 o;
  o.x = f2bf((v.x - mu) * inv * gg.x + bb.x);
  o.y = f2bf((v.y - mu) * inv * gg.y + bb.y);
  o.z = f2bf((v.z - mu) * inv * gg.z + bb.z);
  o.w = f2bf((v.w - mu) * inv * gg.w + bb.w);
  ((ushort4*)(out + (size_t)row * kD))[tid] = o;
}

// ---------------------------------------------------------------------------
// bf16 MFMA GEMM: C[M,N] = A[M,K] * W[N,K]^T  (+bias)(+softplus/gelu)(+=C)
// 128x128 tile, BK=64, 4 waves (2x2), wave does 64x64 via 16x16x32 MFMA.
// AMAP: A rows indexed through segment-compact mapping (REV flips L).
// CMAP: C rows through segment-compact mapping. WF32: W fp32->bf16 in staging,
// rows >= wrows read as zero (x_proj pad).
// ---------------------------------------------------------------------------
template <int ACT, bool BIAS, bool ACC, bool OUTBF, bool REV, bool WF32,
          bool AMAP, bool CMAP>
__global__ __launch_bounds__(256) void gemm_mfma(
    const u16* __restrict__ A, int lda,
    const void* __restrict__ W, int ldw, int wrows,
    void* __restrict__ Cp, int ldc, int K,
    const float* __restrict__ bias, int seg_len, int row_off) {
  __shared__ __align__(16) u16 As[128][72];
  __shared__ __align__(16) u16 Ws[128][72];
  const int tid  = threadIdx.x;
  const int bm   = blockIdx.x * 128;
  const int bn   = blockIdx.y * 128;
  const int lane = tid & 63;
  const int wave = tid >> 6;
  const int wm   = (wave >> 1) * 64;
  const int wn   = (wave & 1) * 64;
  const int l15  = lane & 15;
  const int quad = lane >> 4;
  const int lrow = tid >> 3;        // 0..31
  const int lcol = (tid & 7) * 8;   // 0..56

  int ab = 0, all0 = bm;
  if (AMAP || CMAP) {
    ab = bm / seg_len;
    all0 = bm - ab * seg_len;
  }

  f32x4 acc[4][4];
  #pragma unroll
  for (int i = 0; i < 4; i++)
    #pragma unroll
    for (int j = 0; j < 4; j++) acc[i][j] = (f32x4){0.f, 0.f, 0.f, 0.f};

  for (int k0 = 0; k0 < K; k0 += 64) {
    #pragma unroll
    for (int it = 0; it < 4; it++) {
      const int rl = it * 32 + lrow;
      int arow;
      if (AMAP) {
        arow = REV ? (ab * kL + kL - 1 - row_off - all0 - rl)
                   : (ab * kL + row_off + all0 + rl);
      } else {
        arow = bm + rl;
      }
      *(int4*)&As[rl][lcol] = *(const int4*)(A + (size_t)arow * lda + k0 + lcol);

      const int rn = bn + rl;
      if (WF32) {
        union { ushort u[8]; int4 v; } pk;
        if (rn < wrows) {
          const float* wp = (const float*)W + (size_t)rn * ldw + k0 + lcol;
          const float4 p = *(const float4*)wp;
          const float4 q = *(const float4*)(wp + 4);
          pk.u[0] = f2bf(p.x); pk.u[1] = f2bf(p.y);
          pk.u[2] = f2bf(p.z); pk.u[3] = f2bf(p.w);
          pk.u[4] = f2bf(q.x); pk.u[5] = f2bf(q.y);
          pk.u[6] = f2bf(q.z); pk.u[7] = f2bf(q.w);
        } else {
          pk.v = (int4){0, 0, 0, 0};
        }
        *(int4*)&Ws[rl][lcol] = pk.v;
      } else {
        *(int4*)&Ws[rl][lcol] =
            *(const int4*)((const u16*)W + (size_t)rn * ldw + k0 + lcol);
      }
    }
    __syncthreads();
    #pragma unroll
    for (int ks = 0; ks < 64; ks += 32) {
      bf16x8 af[4], wf[4];
      #pragma unroll
      for (int i = 0; i < 4; i++)
        af[i] = *(const bf16x8*)&As[wm + i * 16 + l15][ks + quad * 8];
      #pragma unroll
      for (int j = 0; j < 4; j++)
        wf[j] = *(const bf16x8*)&Ws[wn + j * 16 + l15][ks + quad * 8];
      #pragma unroll
      for (int i = 0; i < 4; i++)
        #pragma unroll
        for (int j = 0; j < 4; j++)
          acc[i][j] = __builtin_amdgcn_mfma_f32_16x16x32_bf16(
              af[i], wf[j], acc[i][j], 0, 0, 0);
    }
    __syncthreads();
  }

  #pragma unroll
  for (int i = 0; i < 4; i++) {
    #pragma unroll
    for (int j = 0; j < 4; j++) {
      const int col = bn + wn + j * 16 + l15;
      #pragma unroll
      for (int r = 0; r < 4; r++) {
        const int rl2 = wm + i * 16 + quad * 4 + r;
        const int crow = CMAP ? (ab * kL + row_off + all0 + rl2) : (bm + rl2);
        float v = acc[i][j][r];
        if (BIAS) v += bias[col];
        if (ACT == 1) v = softplusf(v);
        if (ACT == 2) v = geluf(v);
        if (OUTBF) {
          ((u16*)Cp)[(size_t)crow * ldc + col] = f2bf(v);
        } else {
          float* p = (float*)Cp + (size_t)crow * ldc + col;
          if (ACC) *p = *p + v; else *p = v;
        }
      }
    }
  }
}

// ---------------------------------------------------------------------------
// Causal depthwise conv (k=4) + bias + silu on one segment (compact rows).
// ---------------------------------------------------------------------------
__global__ __launch_bounds__(256) void conv_silu_kernel(
    const u16* __restrict__ xz, const float* __restrict__ w,
    const float* __restrict__ cb, u16* __restrict__ xs,
    const u16* __restrict__ tail_in, u16* __restrict__ tail_out,
    int seg_len, int row_off) {
  const int t = blockIdx.x * 256 + threadIdx.x;  // Mseg*kDI threads
  const int c = t & (kDI - 1);
  const int r = t >> 11;              // compact row
  const int b = r / seg_len;
  const int ll = r - b * seg_len;
  const int tpos = row_off + ll;      // processing-order position in [0,L)

  const float xv0 = bf2f(xz[(size_t)r * (2 * kDI) + c]);
  float acc = cb[c] + w[c * 4 + 3] * xv0;
  #pragma unroll
  for (int j = 1; j <= 3; j++) {
    if (tpos - j >= 0) {
      float xp;
      if (ll - j >= 0) {
        xp = bf2f(xz[(size_t)(r - j) * (2 * kDI) + c]);
      } else {
        xp = bf2f(tail_in[(b * 3 + (3 + ll - j)) * kDI + c]);
      }
      acc += w[c * 4 + 3 - j] * xp;
    }
  }
  xs[(size_t)r * kDI + c] = f2bf(siluf(acc));
  if (ll >= seg_len - 3) {
    tail_out[(b * 3 + (ll - (seg_len - 3))) * kDI + c] = f2bf(xv0);
  }
}

// ---------------------------------------------------------------------------
// Scan phase A: per (b, c, chunk), 16 states in registers, no cross-lane.
// Computes chunk decay product P[16] and local end-state hloc[16].
// ---------------------------------------------------------------------------
__global__ __launch_bounds__(256) void scan_phaseA(
    const float* __restrict__ dt, const u16* __restrict__ xs,
    const u16* __restrict__ dbl, const float* __restrict__ Alog,
    float* __restrict__ Pbuf, float* __restrict__ Hbuf,
    int Lseg, int Lc) {
  __shared__ float Bls[128][16];
  const int tid = threadIdx.x;
  const int c = blockIdx.x * 256 + tid;
  const int k = blockIdx.y;
  const int b = blockIdx.z;
  const int base = b * Lseg + k * Lc;
  for (int idx = tid; idx < Lc * 16; idx += 256) {
    const int r = idx >> 4, j = idx & 15;
    Bls[r][j] = bf2f(dbl[(size_t)(base + r) * kNPad + kDtRank + j]);
  }
  __syncthreads();
  float Ac[16], h[16], P[16];
  #pragma unroll
  for (int s = 0; s < 16; s++) {
    Ac[s] = -__expf(Alog[c * kDS + s]);
    h[s] = 0.f;
    P[s] = 1.f;
  }
  for (int r = 0; r < Lc; r++) {
    const size_t row = (size_t)(base + r);
    const float dtv = dt[row * kDI + c];
    const float dtx = dtv * bf2f(xs[row * kDI + c]);
    const float4* Brow = (const float4*)Bls[r];
    #pragma unroll
    for (int s4 = 0; s4 < 4; s4++) {
      const float4 Bv = Brow[s4];
      const float bb[4] = {Bv.x, Bv.y, Bv.z, Bv.w};
      #pragma unroll
      for (int q = 0; q < 4; q++) {
        const int s = s4 * 4 + q;
        const float dA = __expf(dtv * Ac[s]);
        h[s] = dA * h[s] + dtx * bb[q];
        P[s] *= dA;
      }
    }
  }
  const size_t o = (((size_t)b * kNCH + k) * kDI + c) * 16;
  #pragma unroll
  for (int s4 = 0; s4 < 4; s4++) {
    *(float4*)&Pbuf[o + s4 * 4] =
        make_float4(P[s4 * 4], P[s4 * 4 + 1], P[s4 * 4 + 2], P[s4 * 4 + 3]);
    *(float4*)&Hbuf[o + s4 * 4] =
        make_float4(h[s4 * 4], h[s4 * 4 + 1], h[s4 * 4 + 2], h[s4 * 4 + 3]);
  }
}

// ---------------------------------------------------------------------------
// Scan phase B: stitch chunks. Writes h_in per chunk over Pbuf; carries
// segment state in hstate.
// ---------------------------------------------------------------------------
__global__ __launch_bounds__(256) void scan_phaseB(
    float* __restrict__ Pbuf, const float* __restrict__ Hbuf,
    float* __restrict__ hstate, int first) {
  const int t = blockIdx.x * 256 + threadIdx.x;  // B*di*16
  const int s = t & 15;
  const int c = (t >> 4) & (kDI - 1);
  const int b = t >> 15;
  float cur = first ? 0.f : hstate[t];
  for (int k = 0; k < kNCH; k++) {
    const size_t idx = (((size_t)b * kNCH + k) * kDI + c) * 16 + s;
    const float p = Pbuf[idx];
    const float hl = Hbuf[idx];
    Pbuf[idx] = cur;
    cur = p * cur + hl;
  }
  hstate[t] = cur;
}

// ---------------------------------------------------------------------------
// Scan phase C: re-run chunk with true h_in (from Pbuf), compute y = C.h,
// apply D residual and silu(z); y overwrites xs (bf16).
// ---------------------------------------------------------------------------
__global__ __launch_bounds__(256) void scan_phaseC(
    const float* __restrict__ dt, u16* __restrict__ xs,
    const u16* __restrict__ dbl, const u16* __restrict__ xz,
    const float* __restrict__ Alog, const float* __restrict__ Dp,
    const float* __restrict__ Pbuf, int Lseg, int Lc) {
  __shared__ float BC[128][32];  // [r][0:16]=B, [r][16:32]=C
  const int tid = threadIdx.x;
  const int c = blockIdx.x * 256 + tid;
  const int k = blockIdx.y;
  const int b = blockIdx.z;
  const int base = b * Lseg + k * Lc;
  for (int idx = tid; idx < Lc * 32; idx += 256) {
    const int r = idx >> 5, j = idx & 31;
    BC[r][j] = bf2f(dbl[(size_t)(base + r) * kNPad + kDtRank + j]);
  }
  __syncthreads();
  float Ac[16], h[16];
  const size_t o = (((size_t)b * kNCH + k) * kDI + c) * 16;
  #pragma unroll
  for (int s4 = 0; s4 < 4; s4++) {
    const float4 hv = *(const float4*)&Pbuf[o + s4 * 4];
    h[s4 * 4 + 0] = hv.x; h[s4 * 4 + 1] = hv.y;
    h[s4 * 4 + 2] = hv.z; h[s4 * 4 + 3] = hv.w;
  }
  #pragma unroll
  for (int s = 0; s < 16; s++) Ac[s] = -__expf(Alog[c * kDS + s]);
  const float Dv = Dp[c];
  for (int r = 0; r < Lc; r++) {
    const size_t row = (size_t)(base + r);
    const float dtv = dt[row * kDI + c];
    const float xv = bf2f(xs[row * kDI + c]);
    const float dtx = dtv * xv;
    float y = 0.f;
    const float4* Brow = (const float4*)BC[r];
    const float4* Crow = (const float4*)&BC[r][16];
    #pragma unroll
    for (int s4 = 0; s4 < 4; s4++) {
      const float4 Bv = Brow[s4];
      const float4 Cv = Crow[s4];
      const float bb[4] = {Bv.x, Bv.y, Bv.z, Bv.w};
      const float cc[4] = {Cv.x, Cv.y, Cv.z, Cv.w};
      #pragma unroll
      for (int q = 0; q < 4; q++) {
        const int s = s4 * 4 + q;
        const float dA = __expf(dtv * Ac[s]);
        h[s] = dA * h[s] + dtx * bb[q];
        y += h[s] * cc[q];
      }
    }
    const float z = bf2f(xz[row * (2 * kDI) + kDI + c]);
    xs[row * kDI + c] = f2bf((y + Dv * xv) * siluf(z));
  }
}

// out = x + gelu(out + x)  in place (out currently holds fwd+bwd, f32)
__global__ __launch_bounds__(256) void combine_kernel(
    const float* __restrict__ x, float* __restrict__ out) {
  const size_t i = (size_t)blockIdx.x * 256 + threadIdx.x;  // M*D/4
  const float4 xv = ((const float4*)x)[i];
  const float4 bv = ((const float4*)out)[i];
  float4 o;
  o.x = xv.x + geluf(bv.x + xv.x);
  o.y = xv.y + geluf(bv.y + xv.y);
  o.z = xv.z + geluf(bv.z + xv.z);
  o.w = xv.w + geluf(bv.w + xv.w);
  ((float4*)out)[i] = o;
}

}  // namespace

extern "C" void kernel_launch(void* const* d_in, const int* in_sizes, int n_in,
                              void* d_out, int out_size, void* d_ws,
                              size_t ws_size, hipStream_t stream) {
  const float* x = (const float*)d_in[0];
  const float* in_w[2]    = {(const float*)d_in[1],  (const float*)d_in[10]};
  const float* conv_w[2]  = {(const float*)d_in[2],  (const float*)d_in[11]};
  const float* conv_b[2]  = {(const float*)d_in[3],  (const float*)d_in[12]};
  const float* xproj_w[2] = {(const float*)d_in[4],  (const float*)d_in[13]};
  const float* dt_w[2]    = {(const float*)d_in[5],  (const float*)d_in[14]};
  const float* dt_b[2]    = {(const float*)d_in[6],  (const float*)d_in[15]};
  const float* Alog[2]    = {(const float*)d_in[7],  (const float*)d_in[16]};
  const float* Dp[2]      = {(const float*)d_in[8],  (const float*)d_in[17]};
  const float* out_w[2]   = {(const float*)d_in[9],  (const float*)d_in[18]};
  const float* norm_g = (const float*)d_in[19];
  const float* norm_b = (const float*)d_in[20];
  const float* ffn_g  = (const float*)d_in[21];
  const float* ffn_b  = (const float*)d_in[22];
  const float* ff1_w  = (const float*)d_in[23];
  const float* ff1_b  = (const float*)d_in[24];
  const float* ff2_w  = (const float*)d_in[25];
  const float* ff2_b  = (const float*)d_in[26];
  float* out = (float*)d_out;

  // --- adaptive workspace layout ---------------------------------------
  auto need = [](int nseg) -> size_t {
    const size_t mseg = (size_t)kM / nseg;
    size_t sz = 0;
    sz += (size_t)kM * kD * 2;            // h bf16
    sz += mseg * 4096 * 2;                // xz bf16 (aliases FFN hidden)
    sz += mseg * 2048 * 2;                // xs bf16
    sz += mseg * 128 * 2;                 // dbl bf16
    sz += mseg * 2048 * 4;                // dt f32
    sz += 2 * (size_t)kB * kNCH * kDI * kDS * 4;  // Pbuf + Hbuf
    sz += (size_t)kB * kDI * kDS * 4;     // hstate
    sz += 2 * (size_t)kB * 3 * kDI * 2;   // conv tails
    sz += 16 * 256;                       // alignment slack
    return sz;
  };
  int nseg = 1;
  while (nseg <= 16 && need(nseg) > ws_size) nseg *= 2;
  if (nseg > 16) return;  // clean fail
  const int Lseg = kL / nseg;
  const int Mseg = kM / nseg;
  const int Lc = Lseg / kNCH;

  char* base = (char*)d_ws;
  size_t off = 0;
  auto alloc = [&](size_t bytes) {
    char* p = base + off;
    off = (off + bytes + 255) & ~(size_t)255;
    return p;
  };
  u16*   h      = (u16*)alloc((size_t)kM * kD * 2);
  u16*   xz     = (u16*)alloc((size_t)Mseg * 4096 * 2);
  u16*   xs     = (u16*)alloc((size_t)Mseg * 2048 * 2);
  u16*   dbl    = (u16*)alloc((size_t)Mseg * 128 * 2);
  float* dtb    = (float*)alloc((size_t)Mseg * 2048 * 4);
  float* Pbuf   = (float*)alloc((size_t)kB * kNCH * kDI * kDS * 4);
  float* Hbuf   = (float*)alloc((size_t)kB * kNCH * kDI * kDS * 4);
  float* hstate = (float*)alloc((size_t)kB * kDI * kDS * 4);
  u16*   tail0  = (u16*)alloc((size_t)kB * 3 * kDI * 2);
  u16*   tail1  = (u16*)alloc((size_t)kB * 3 * kDI * 2);

  // LN(x) -> h (bf16)
  ln_kernel<<<kM, 256, 0, stream>>>(x, norm_g, norm_b, h);

  for (int m = 0; m < 2; m++) {
    for (int s = 0; s < nseg; s++) {
      const int l0 = s * Lseg;
      u16* tin  = (s & 1) ? tail0 : tail1;
      u16* tout = (s & 1) ? tail1 : tail0;
      // in_proj: h rows (REV for m=1) x in_w[4096,1024]^T -> xz [Mseg,4096]
      if (m == 0)
        gemm_mfma<0, false, false, true, false, true, true, false>
            <<<dim3(Mseg / 128, 4096 / 128), 256, 0, stream>>>(
                h, kD, in_w[m], kD, 4096, xz, 4096, kD, nullptr, Lseg, l0);
      else
        gemm_mfma<0, false, false, true, true, true, true, false>
            <<<dim3(Mseg / 128, 4096 / 128), 256, 0, stream>>>(
                h, kD, in_w[m], kD, 4096, xz, 4096, kD, nullptr, Lseg, l0);
      // causal depthwise conv + silu -> xs
      conv_silu_kernel<<<(Mseg * kDI) / 256, 256, 0, stream>>>(
          xz, conv_w[m], conv_b[m], xs, tin, tout, Lseg, l0);
      // x_proj: xs x xproj[96->128,2048]^T -> dbl bf16 [Mseg,128]
      gemm_mfma<0, false, false, true, false, true, false, false>
          <<<dim3(Mseg / 128, 1), 256, 0, stream>>>(
              xs, kDI, xproj_w[m], kDI, kDtRank + 2 * kDS, dbl, kNPad, kDI,
              nullptr, Lseg, l0);
      // dt_proj + softplus: dbl[:, :64] x dt_w[2048,64]^T -> dt f32 [Mseg,2048]
      gemm_mfma<1, true, false, false, false, true, false, false>
          <<<dim3(Mseg / 128, kDI / 128), 256, 0, stream>>>(
              dbl, kNPad, dt_w[m], kDtRank, kDI, dtb, kDI, kDtRank,
              dt_b[m], Lseg, l0);
      // chunked scan: A (local), B (stitch), C (emit y into xs)
      scan_phaseA<<<dim3(kDI / 256, kNCH, kB), 256, 0, stream>>>(
          dtb, xs, dbl, Alog[m], Pbuf, Hbuf, Lseg, Lc);
      scan_phaseB<<<(kB * kDI * kDS) / 256, 256, 0, stream>>>(
          Pbuf, Hbuf, hstate, (s == 0) ? 1 : 0);
      scan_phaseC<<<dim3(kDI / 256, kNCH, kB), 256, 0, stream>>>(
          dtb, xs, dbl, xz, Alog[m], Dp[m], Pbuf, Lseg, Lc);
      // out_proj -> d_out rows (f32); m=1 accumulates
      if (m == 0)
        gemm_mfma<0, false, false, false, false, true, false, true>
            <<<dim3(Mseg / 128, kD / 128), 256, 0, stream>>>(
                xs, kDI, out_w[m], kDI, kD, out, kD, kDI, nullptr, Lseg, l0);
      else
        gemm_mfma<0, false, true, false, false, true, false, true>
            <<<dim3(Mseg / 128, kD / 128), 256, 0, stream>>>(
                xs, kDI, out_w[m], kDI, kD, out, kD, kDI, nullptr, Lseg, l0);
    }
  }

  // x2 = x + gelu(fwd + bwd + x), in place on d_out
  combine_kernel<<<(kM * kD) / 1024, 256, 0, stream>>>(x, out);

  // FFN: LN(x2) -> h ; per M-segment: hidden = gelu(h@ff1^T+b1) (alias xz);
  // out += hidden@ff2^T + b2
  ln_kernel<<<kM, 256, 0, stream>>>(out, ffn_g, ffn_b, h);
  for (int s = 0; s < nseg; s++) {
    const int r0 = s * Mseg;
    gemm_mfma<2, true, false, true, false, true, true, false>
        <<<dim3(Mseg / 128, kDFF / 128), 256, 0, stream>>>(
            h, kD, ff1_w, kD, kDFF, xz, kDFF, kD, ff1_b, Mseg, r0);
    gemm_mfma<0, true, true, false, false, true, false, true>
        <<<dim3(Mseg / 128, kD / 128), 256, 0, stream>>>(
            xz, kDFF, ff2_w, kDFF, kD, out, kD, kDFF, ff2_b, Mseg, r0);
  }
}

// Round 5
// 1649.296 us; speedup vs baseline: 4.2749x; 1.3299x over previous
//
#include <hip/hip_runtime.h>
#include <cmath>

// ---------------------------------------------------------------------------
// BiDirectionalAddFFBlock: LN -> mamba(fwd)+mamba(rev) -> gelu residual ->
// LN -> FFN.  B=4, L=2048, D=1024, di=2048, ds=16, dt_rank=64, DFF=4096.
// Round 5: GEMMs were the bottleneck (238us, MfmaUtil 11%, 8.4M LDS bank
// conflicts).  Rebuilt on the m97 structure: async global_load_lds width=16
// staging into unpadded [128][64] LDS, BK=64, bf16 weight cache pre-converted
// once per call (kills WF32 in-staging convert).  dt buffer bf16.
// ---------------------------------------------------------------------------

namespace {

using u16 = unsigned short;
using uint = unsigned int;

constexpr int kB = 4;
constexpr int kL = 2048;
constexpr int kD = 1024;
constexpr int kDI = 2048;
constexpr int kDFF = 4096;
constexpr int kDS = 16;
constexpr int kDtRank = 64;
constexpr int kNPad = 128;       // x_proj N=96 padded to 128
constexpr int kM = kB * kL;      // 8192 rows
constexpr int kNCH = 16;         // scan chunks per segment

typedef short bf16x8 __attribute__((ext_vector_type(8)));
typedef float f32x4  __attribute__((ext_vector_type(4)));

__device__ __forceinline__ float bf2f(u16 u) {
  union { unsigned int i; float f; } c; c.i = ((unsigned int)u) << 16; return c.f;
}
__device__ __forceinline__ u16 f2bf(float f) {  // round-to-nearest-even
  union { float f; unsigned int i; } c; c.f = f;
  return (u16)((c.i + 0x7FFFu + ((c.i >> 16) & 1u)) >> 16);
}
__device__ __forceinline__ float geluf(float v) {
  return 0.5f * v * (1.f + erff(v * 0.70710678118654752f));
}
__device__ __forceinline__ float softplusf(float v) {
  return (v > 0.f) ? (v + log1pf(__expf(-v))) : log1pf(__expf(v));
}
__device__ __forceinline__ float siluf(float v) {
  return v / (1.f + __expf(-v));
}

// async 16B global -> LDS (dest = wave-uniform lds base + lane*16)
__device__ __forceinline__ void async16(const u16* g, u16* l) {
  __builtin_amdgcn_global_load_lds(
      (const __attribute__((address_space(1))) uint*)g,
      (__attribute__((address_space(3))) uint*)l, 16, 0, 0);
}

// ---------------------------------------------------------------------------
// LayerNorm fp32 row (1024) -> bf16.  One block per row.
// ---------------------------------------------------------------------------
__global__ __launch_bounds__(256) void ln_kernel(
    const float* __restrict__ x, const float* __restrict__ g,
    const float* __restrict__ b, u16* __restrict__ out) {
  const int row = blockIdx.x;
  const int tid = threadIdx.x;
  const float4 v = ((const float4*)(x + (size_t)row * kD))[tid];
  float s  = v.x + v.y + v.z + v.w;
  float ss = v.x * v.x + v.y * v.y + v.z * v.z + v.w * v.w;
  #pragma unroll
  for (int off = 32; off; off >>= 1) {
    s  += __shfl_xor(s, off);
    ss += __shfl_xor(ss, off);
  }
  __shared__ float ls[4], lss[4];
  const int wid = tid >> 6;
  if ((tid & 63) == 0) { ls[wid] = s; lss[wid] = ss; }
  __syncthreads();
  s  = ls[0] + ls[1] + ls[2] + ls[3];
  ss = lss[0] + lss[1] + lss[2] + lss[3];
  const float mu  = s * (1.f / kD);
  const float inv = rsqrtf(ss * (1.f / kD) - mu * mu + 1e-5f);
  const float4 gg = ((const float4*)g)[tid];
  const float4 bb = ((const float4*)b)[tid];
  ushort4 o;
  o.x = f2bf((v.x - mu) * inv * gg.x + bb.x);
  o.y = f2bf((v.y - mu) * inv * gg.y + bb.y);
  o.z = f2bf((v.z - mu) * inv * gg.z + bb.z);
  o.w = f2bf((v.w - mu) * inv * gg.w + bb.w);
  ((ushort4*)(out + (size_t)row * kD))[tid] = o;
}

// fp32 -> bf16 convert, count divisible by 1024
__global__ __launch_bounds__(256) void cvt_kernel(
    const float* __restrict__ s, u16* __restrict__ d) {
  const int i = blockIdx.x * 256 + threadIdx.x;
  const float4 v = ((const float4*)s)[i];
  ushort4 o = { f2bf(v.x), f2bf(v.y), f2bf(v.z), f2bf(v.w) };
  ((ushort4*)d)[i] = o;
}

// xproj_w [96,2048] fp32 -> [128,2048] bf16 zero-padded
__global__ __launch_bounds__(256) void cvt_xproj_kernel(
    const float* __restrict__ s, u16* __restrict__ d) {
  const int i = blockIdx.x * 256 + threadIdx.x;  // over 128*2048/4
  const int r = (i * 4) / kDI;
  ushort4 o = {0, 0, 0, 0};
  if (r < kDtRank + 2 * kDS) {
    const float4 v = ((const float4*)s)[i];
    o.x = f2bf(v.x); o.y = f2bf(v.y); o.z = f2bf(v.z); o.w = f2bf(v.w);
  }
  ((ushort4*)d)[i] = o;
}

// ---------------------------------------------------------------------------
// bf16 MFMA GEMM (m97 structure): C[M,N] = A[M,K] * W[N,K]^T  (+bias)(+act)
// (+=C).  128x128 tile, BK=64, 4 waves (2x2), each 64x64 via 16x16x32 MFMA.
// Staging: global_load_lds width=16 into unpadded As/Ws[128][64]; wave w
// stages 8-row strips (lane i -> row i/8, col (i%8)*8; LDS dest base is
// wave-uniform so dest = base + lane*16 matches the row-major strip).
// AMAP/CMAP: segment-compact row mapping (REV flips L within batch).
// ---------------------------------------------------------------------------
template <int ACT, bool BIAS, bool ACC, bool OUTBF, bool REV, bool AMAP,
          bool CMAP>
__global__ __launch_bounds__(256) void gemm_mfma(
    const u16* __restrict__ A, int lda,
    const u16* __restrict__ W, int ldw,
    void* __restrict__ Cp, int ldc, int K,
    const float* __restrict__ bias, int seg_len, int row_off) {
  __shared__ __align__(16) u16 As[128][64];
  __shared__ __align__(16) u16 Ws[128][64];
  const int tid  = threadIdx.x;
  const int bm   = blockIdx.x * 128;
  const int bn   = blockIdx.y * 128;
  const int lane = tid & 63;
  const int wv   = tid >> 6;
  const int wm   = (wv >> 1) * 64;
  const int wn   = (wv & 1) * 64;
  const int l15  = lane & 15;
  const int quad = lane >> 4;
  const int srow = lane >> 3;        // 0..7 within the 8-row strip
  const int scol = (lane & 7) * 8;   // u16 col within the 64-col tile

  int ab = 0, all0 = bm;
  if (AMAP || CMAP) {
    ab = bm / seg_len;
    all0 = bm - ab * seg_len;
  }

  // per-strip A global rows (strip it covers rows it*32 + wv*8 + srow)
  int arowv[4];
  #pragma unroll
  for (int it = 0; it < 4; it++) {
    const int rl = it * 32 + wv * 8 + srow;
    if (AMAP) {
      arowv[it] = REV ? (ab * kL + kL - 1 - row_off - all0 - rl)
                      : (ab * kL + row_off + all0 + rl);
    } else {
      arowv[it] = bm + rl;
    }
  }

  f32x4 acc[4][4];
  #pragma unroll
  for (int i = 0; i < 4; i++)
    #pragma unroll
    for (int j = 0; j < 4; j++) acc[i][j] = (f32x4){0.f, 0.f, 0.f, 0.f};

  for (int k0 = 0; k0 < K; k0 += 64) {
    #pragma unroll
    for (int it = 0; it < 4; it++) {
      const int rl = it * 32 + wv * 8 + srow;
      async16(A + (size_t)arowv[it] * lda + k0 + scol, &As[it * 32 + wv * 8][0]);
      async16(W + (size_t)(bn + rl) * ldw + k0 + scol, &Ws[it * 32 + wv * 8][0]);
    }
    __syncthreads();
    #pragma unroll
    for (int ks = 0; ks < 64; ks += 32) {
      bf16x8 af[4], wf[4];
      #pragma unroll
      for (int i = 0; i < 4; i++)
        af[i] = *(const bf16x8*)&As[wm + i * 16 + l15][ks + quad * 8];
      #pragma unroll
      for (int j = 0; j < 4; j++)
        wf[j] = *(const bf16x8*)&Ws[wn + j * 16 + l15][ks + quad * 8];
      #pragma unroll
      for (int i = 0; i < 4; i++)
        #pragma unroll
        for (int j = 0; j < 4; j++)
          acc[i][j] = __builtin_amdgcn_mfma_f32_16x16x32_bf16(
              af[i], wf[j], acc[i][j], 0, 0, 0);
    }
    __syncthreads();
  }

  #pragma unroll
  for (int i = 0; i < 4; i++) {
    #pragma unroll
    for (int j = 0; j < 4; j++) {
      const int col = bn + wn + j * 16 + l15;
      #pragma unroll
      for (int r = 0; r < 4; r++) {
        const int rl2 = wm + i * 16 + quad * 4 + r;
        const int crow = CMAP ? (ab * kL + row_off + all0 + rl2) : (bm + rl2);
        float v = acc[i][j][r];
        if (BIAS) v += bias[col];
        if (ACT == 1) v = softplusf(v);
        if (ACT == 2) v = geluf(v);
        if (OUTBF) {
          ((u16*)Cp)[(size_t)crow * ldc + col] = f2bf(v);
        } else {
          float* p = (float*)Cp + (size_t)crow * ldc + col;
          if (ACC) *p = *p + v; else *p = v;
        }
      }
    }
  }
}

// ---------------------------------------------------------------------------
// Causal depthwise conv (k=4) + bias + silu on one segment (compact rows).
// ---------------------------------------------------------------------------
__global__ __launch_bounds__(256) void conv_silu_kernel(
    const u16* __restrict__ xz, const float* __restrict__ w,
    const float* __restrict__ cb, u16* __restrict__ xs,
    const u16* __restrict__ tail_in, u16* __restrict__ tail_out,
    int seg_len, int row_off) {
  const int t = blockIdx.x * 256 + threadIdx.x;  // Mseg*kDI threads
  const int c = t & (kDI - 1);
  const int r = t >> 11;              // compact row
  const int b = r / seg_len;
  const int ll = r - b * seg_len;
  const int tpos = row_off + ll;      // processing-order position in [0,L)

  const float xv0 = bf2f(xz[(size_t)r * (2 * kDI) + c]);
  float acc = cb[c] + w[c * 4 + 3] * xv0;
  #pragma unroll
  for (int j = 1; j <= 3; j++) {
    if (tpos - j >= 0) {
      float xp;
      if (ll - j >= 0) {
        xp = bf2f(xz[(size_t)(r - j) * (2 * kDI) + c]);
      } else {
        xp = bf2f(tail_in[(b * 3 + (3 + ll - j)) * kDI + c]);
      }
      acc += w[c * 4 + 3 - j] * xp;
    }
  }
  xs[(size_t)r * kDI + c] = f2bf(siluf(acc));
  if (ll >= seg_len - 3) {
    tail_out[(b * 3 + (ll - (seg_len - 3))) * kDI + c] = f2bf(xv0);
  }
}

// ---------------------------------------------------------------------------
// Scan phase A: per (b, c, chunk), 16 states in registers, no cross-lane.
// ---------------------------------------------------------------------------
__global__ __launch_bounds__(256) void scan_phaseA(
    const u16* __restrict__ dt, const u16* __restrict__ xs,
    const u16* __restrict__ dbl, const float* __restrict__ Alog,
    float* __restrict__ Pbuf, float* __restrict__ Hbuf,
    int Lseg, int Lc) {
  __shared__ float Bls[128][16];
  const int tid = threadIdx.x;
  const int c = blockIdx.x * 256 + tid;
  const int k = blockIdx.y;
  const int b = blockIdx.z;
  const int base = b * Lseg + k * Lc;
  for (int idx = tid; idx < Lc * 16; idx += 256) {
    const int r = idx >> 4, j = idx & 15;
    Bls[r][j] = bf2f(dbl[(size_t)(base + r) * kNPad + kDtRank + j]);
  }
  __syncthreads();
  float Ac[16], h[16], P[16];
  #pragma unroll
  for (int s = 0; s < 16; s++) {
    Ac[s] = -__expf(Alog[c * kDS + s]);
    h[s] = 0.f;
    P[s] = 1.f;
  }
  for (int r = 0; r < Lc; r++) {
    const size_t row = (size_t)(base + r);
    const float dtv = bf2f(dt[row * kDI + c]);
    const float dtx = dtv * bf2f(xs[row * kDI + c]);
    const float4* Brow = (const float4*)Bls[r];
    #pragma unroll
    for (int s4 = 0; s4 < 4; s4++) {
      const float4 Bv = Brow[s4];
      const float bb[4] = {Bv.x, Bv.y, Bv.z, Bv.w};
      #pragma unroll
      for (int q = 0; q < 4; q++) {
        const int s = s4 * 4 + q;
        const float dA = __expf(dtv * Ac[s]);
        h[s] = dA * h[s] + dtx * bb[q];
        P[s] *= dA;
      }
    }
  }
  const size_t o = (((size_t)b * kNCH + k) * kDI + c) * 16;
  #pragma unroll
  for (int s4 = 0; s4 < 4; s4++) {
    *(float4*)&Pbuf[o + s4 * 4] =
        make_float4(P[s4 * 4], P[s4 * 4 + 1], P[s4 * 4 + 2], P[s4 * 4 + 3]);
    *(float4*)&Hbuf[o + s4 * 4] =
        make_float4(h[s4 * 4], h[s4 * 4 + 1], h[s4 * 4 + 2], h[s4 * 4 + 3]);
  }
}

// ---------------------------------------------------------------------------
// Scan phase B: stitch chunks; h_in per chunk written over Pbuf.
// ---------------------------------------------------------------------------
__global__ __launch_bounds__(256) void scan_phaseB(
    float* __restrict__ Pbuf, const float* __restrict__ Hbuf,
    float* __restrict__ hstate, int first) {
  const int t = blockIdx.x * 256 + threadIdx.x;  // B*di*16
  const int s = t & 15;
  const int c = (t >> 4) & (kDI - 1);
  const int b = t >> 15;
  float cur = first ? 0.f : hstate[t];
  for (int k = 0; k < kNCH; k++) {
    const size_t idx = (((size_t)b * kNCH + k) * kDI + c) * 16 + s;
    const float p = Pbuf[idx];
    const float hl = Hbuf[idx];
    Pbuf[idx] = cur;
    cur = p * cur + hl;
  }
  hstate[t] = cur;
}

// ---------------------------------------------------------------------------
// Scan phase C: re-run chunk with true h_in, y = C.h + D*x, *silu(z) -> xs.
// ---------------------------------------------------------------------------
__global__ __launch_bounds__(256) void scan_phaseC(
    const u16* __restrict__ dt, u16* __restrict__ xs,
    const u16* __restrict__ dbl, const u16* __restrict__ xz,
    const float* __restrict__ Alog, const float* __restrict__ Dp,
    const float* __restrict__ Pbuf, int Lseg, int Lc) {
  __shared__ float BC[128][32];  // [r][0:16]=B, [r][16:32]=C
  const int tid = threadIdx.x;
  const int c = blockIdx.x * 256 + tid;
  const int k = blockIdx.y;
  const int b = blockIdx.z;
  const int base = b * Lseg + k * Lc;
  for (int idx = tid; idx < Lc * 32; idx += 256) {
    const int r = idx >> 5, j = idx & 31;
    BC[r][j] = bf2f(dbl[(size_t)(base + r) * kNPad + kDtRank + j]);
  }
  __syncthreads();
  float Ac[16], h[16];
  const size_t o = (((size_t)b * kNCH + k) * kDI + c) * 16;
  #pragma unroll
  for (int s4 = 0; s4 < 4; s4++) {
    const float4 hv = *(const float4*)&Pbuf[o + s4 * 4];
    h[s4 * 4 + 0] = hv.x; h[s4 * 4 + 1] = hv.y;
    h[s4 * 4 + 2] = hv.z; h[s4 * 4 + 3] = hv.w;
  }
  #pragma unroll
  for (int s = 0; s < 16; s++) Ac[s] = -__expf(Alog[c * kDS + s]);
  const float Dv = Dp[c];
  for (int r = 0; r < Lc; r++) {
    const size_t row = (size_t)(base + r);
    const float dtv = bf2f(dt[row * kDI + c]);
    const float xv = bf2f(xs[row * kDI + c]);
    const float dtx = dtv * xv;
    float y = 0.f;
    const float4* Brow = (const float4*)BC[r];
    const float4* Crow = (const float4*)&BC[r][16];
    #pragma unroll
    for (int s4 = 0; s4 < 4; s4++) {
      const float4 Bv = Brow[s4];
      const float4 Cv = Crow[s4];
      const float bb[4] = {Bv.x, Bv.y, Bv.z, Bv.w};
      const float cc[4] = {Cv.x, Cv.y, Cv.z, Cv.w};
      #pragma unroll
      for (int q = 0; q < 4; q++) {
        const int s = s4 * 4 + q;
        const float dA = __expf(dtv * Ac[s]);
        h[s] = dA * h[s] + dtx * bb[q];
        y += h[s] * cc[q];
      }
    }
    const float z = bf2f(xz[row * (2 * kDI) + kDI + c]);
    xs[row * kDI + c] = f2bf((y + Dv * xv) * siluf(z));
  }
}

// out = x + gelu(out + x)  in place (out currently holds fwd+bwd, f32)
__global__ __launch_bounds__(256) void combine_kernel(
    const float* __restrict__ x, float* __restrict__ out) {
  const size_t i = (size_t)blockIdx.x * 256 + threadIdx.x;  // M*D/4
  const float4 xv = ((const float4*)x)[i];
  const float4 bv = ((const float4*)out)[i];
  float4 o;
  o.x = xv.x + geluf(bv.x + xv.x);
  o.y = xv.y + geluf(bv.y + xv.y);
  o.z = xv.z + geluf(bv.z + xv.z);
  o.w = xv.w + geluf(bv.w + xv.w);
  ((float4*)out)[i] = o;
}

}  // namespace

extern "C" void kernel_launch(void* const* d_in, const int* in_sizes, int n_in,
                              void* d_out, int out_size, void* d_ws,
                              size_t ws_size, hipStream_t stream) {
  const float* x = (const float*)d_in[0];
  const float* in_w[2]    = {(const float*)d_in[1],  (const float*)d_in[10]};
  const float* conv_w[2]  = {(const float*)d_in[2],  (const float*)d_in[11]};
  const float* conv_b[2]  = {(const float*)d_in[3],  (const float*)d_in[12]};
  const float* xproj_w[2] = {(const float*)d_in[4],  (const float*)d_in[13]};
  const float* dt_w[2]    = {(const float*)d_in[5],  (const float*)d_in[14]};
  const float* dt_b[2]    = {(const float*)d_in[6],  (const float*)d_in[15]};
  const float* Alog[2]    = {(const float*)d_in[7],  (const float*)d_in[16]};
  const float* Dp[2]      = {(const float*)d_in[8],  (const float*)d_in[17]};
  const float* out_w[2]   = {(const float*)d_in[9],  (const float*)d_in[18]};
  const float* norm_g = (const float*)d_in[19];
  const float* norm_b = (const float*)d_in[20];
  const float* ffn_g  = (const float*)d_in[21];
  const float* ffn_b  = (const float*)d_in[22];
  const float* ff1_w  = (const float*)d_in[23];
  const float* ff1_b  = (const float*)d_in[24];
  const float* ff2_w  = (const float*)d_in[25];
  const float* ff2_b  = (const float*)d_in[26];
  float* out = (float*)d_out;

  // --- adaptive workspace layout ---------------------------------------
  constexpr size_t kWCache =
      2 * ((size_t)4096 * kD + (size_t)kD * kDI + (size_t)kNPad * kDI +
           (size_t)kDI * kDtRank) * 2 +
      ((size_t)kDFF * kD + (size_t)kD * kDFF) * 2;  // bf16 weights
  auto need = [](int nseg) -> size_t {
    const size_t mseg = (size_t)kM / nseg;
    size_t sz = kWCache + 4096;
    sz += (size_t)kM * kD * 2;            // h bf16
    sz += mseg * 4096 * 2;                // xz bf16 (aliases FFN hidden)
    sz += mseg * 2048 * 2;                // xs bf16
    sz += mseg * 128 * 2;                 // dbl bf16
    sz += mseg * 2048 * 2;                // dt bf16
    sz += 2 * (size_t)kB * kNCH * kDI * kDS * 4;  // Pbuf + Hbuf
    sz += (size_t)kB * kDI * kDS * 4;     // hstate
    sz += 2 * (size_t)kB * 3 * kDI * 2;   // conv tails
    sz += 32 * 256;                       // alignment slack
    return sz;
  };
  int nseg = 1;
  while (nseg <= 16 && need(nseg) > ws_size) nseg *= 2;
  if (nseg > 16) return;  // clean fail
  const int Lseg = kL / nseg;
  const int Mseg = kM / nseg;
  const int Lc = Lseg / kNCH;

  char* base = (char*)d_ws;
  size_t off = 0;
  auto alloc = [&](size_t bytes) {
    char* p = base + off;
    off = (off + bytes + 255) & ~(size_t)255;
    return p;
  };
  // bf16 weight cache
  u16* w_in[2], *w_out[2], *w_xp[2], *w_dt[2];
  for (int m = 0; m < 2; m++) {
    w_in[m]  = (u16*)alloc((size_t)4096 * kD * 2);
    w_out[m] = (u16*)alloc((size_t)kD * kDI * 2);
    w_xp[m]  = (u16*)alloc((size_t)kNPad * kDI * 2);
    w_dt[m]  = (u16*)alloc((size_t)kDI * kDtRank * 2);
  }
  u16* w_f1 = (u16*)alloc((size_t)kDFF * kD * 2);
  u16* w_f2 = (u16*)alloc((size_t)kD * kDFF * 2);
  // activations
  u16*   h      = (u16*)alloc((size_t)kM * kD * 2);
  u16*   xz     = (u16*)alloc((size_t)Mseg * 4096 * 2);
  u16*   xs     = (u16*)alloc((size_t)Mseg * 2048 * 2);
  u16*   dbl    = (u16*)alloc((size_t)Mseg * 128 * 2);
  u16*   dtb    = (u16*)alloc((size_t)Mseg * 2048 * 2);
  float* Pbuf   = (float*)alloc((size_t)kB * kNCH * kDI * kDS * 4);
  float* Hbuf   = (float*)alloc((size_t)kB * kNCH * kDI * kDS * 4);
  float* hstate = (float*)alloc((size_t)kB * kDI * kDS * 4);
  u16*   tail0  = (u16*)alloc((size_t)kB * 3 * kDI * 2);
  u16*   tail1  = (u16*)alloc((size_t)kB * 3 * kDI * 2);

  // weight conversion (once per call)
  for (int m = 0; m < 2; m++) {
    cvt_kernel<<<(4096 * kD) / 1024, 256, 0, stream>>>(in_w[m], w_in[m]);
    cvt_kernel<<<(kD * kDI) / 1024, 256, 0, stream>>>(out_w[m], w_out[m]);
    cvt_xproj_kernel<<<(kNPad * kDI) / 1024, 256, 0, stream>>>(xproj_w[m],
                                                               w_xp[m]);
    cvt_kernel<<<(kDI * kDtRank) / 1024, 256, 0, stream>>>(dt_w[m], w_dt[m]);
  }
  cvt_kernel<<<(kDFF * kD) / 1024, 256, 0, stream>>>(ff1_w, w_f1);
  cvt_kernel<<<(kD * kDFF) / 1024, 256, 0, stream>>>(ff2_w, w_f2);

  // LN(x) -> h (bf16)
  ln_kernel<<<kM, 256, 0, stream>>>(x, norm_g, norm_b, h);

  for (int m = 0; m < 2; m++) {
    for (int s = 0; s < nseg; s++) {
      const int l0 = s * Lseg;
      u16* tin  = (s & 1) ? tail0 : tail1;
      u16* tout = (s & 1) ? tail1 : tail0;
      // in_proj: h rows (REV for m=1) x in_w[4096,1024]^T -> xz [Mseg,4096]
      if (m == 0)
        gemm_mfma<0, false, false, true, false, true, false>
            <<<dim3(Mseg / 128, 4096 / 128), 256, 0, stream>>>(
                h, kD, w_in[m], kD, xz, 4096, kD, nullptr, Lseg, l0);
      else
        gemm_mfma<0, false, false, true, true, true, false>
            <<<dim3(Mseg / 128, 4096 / 128), 256, 0, stream>>>(
                h, kD, w_in[m], kD, xz, 4096, kD, nullptr, Lseg, l0);
      // causal depthwise conv + silu -> xs
      conv_silu_kernel<<<(Mseg * kDI) / 256, 256, 0, stream>>>(
          xz, conv_w[m], conv_b[m], xs, tin, tout, Lseg, l0);
      // x_proj: xs x xproj[128(pad),2048]^T -> dbl bf16 [Mseg,128]
      gemm_mfma<0, false, false, true, false, false, false>
          <<<dim3(Mseg / 128, 1), 256, 0, stream>>>(
              xs, kDI, w_xp[m], kDI, dbl, kNPad, kDI, nullptr, Lseg, l0);
      // dt_proj + softplus: dbl[:, :64] x dt_w[2048,64]^T -> dt bf16
      gemm_mfma<1, true, false, true, false, false, false>
          <<<dim3(Mseg / 128, kDI / 128), 256, 0, stream>>>(
              dbl, kNPad, w_dt[m], kDtRank, dtb, kDI, kDtRank, dt_b[m],
              Lseg, l0);
      // chunked scan: A (local), B (stitch), C (emit y into xs)
      scan_phaseA<<<dim3(kDI / 256, kNCH, kB), 256, 0, stream>>>(
          dtb, xs, dbl, Alog[m], Pbuf, Hbuf, Lseg, Lc);
      scan_phaseB<<<(kB * kDI * kDS) / 256, 256, 0, stream>>>(
          Pbuf, Hbuf, hstate, (s == 0) ? 1 : 0);
      scan_phaseC<<<dim3(kDI / 256, kNCH, kB), 256, 0, stream>>>(
          dtb, xs, dbl, xz, Alog[m], Dp[m], Pbuf, Lseg, Lc);
      // out_proj -> d_out rows (f32); m=1 accumulates
      if (m == 0)
        gemm_mfma<0, false, false, false, false, false, true>
            <<<dim3(Mseg / 128, kD / 128), 256, 0, stream>>>(
                xs, kDI, w_out[m], kDI, out, kD, kDI, nullptr, Lseg, l0);
      else
        gemm_mfma<0, false, true, false, false, false, true>
            <<<dim3(Mseg / 128, kD / 128), 256, 0, stream>>>(
                xs, kDI, w_out[m], kDI, out, kD, kDI, nullptr, Lseg, l0);
    }
  }

  // x2 = x + gelu(fwd + bwd + x), in place on d_out
  combine_kernel<<<(kM * kD) / 1024, 256, 0, stream>>>(x, out);

  // FFN: LN(x2) -> h ; per M-segment: hidden = gelu(h@ff1^T+b1) (alias xz);
  // out += hidden@ff2^T + b2
  ln_kernel<<<kM, 256, 0, stream>>>(out, ffn_g, ffn_b, h);
  for (int s = 0; s < nseg; s++) {
    const int r0 = s * Mseg;
    gemm_mfma<2, true, false, true, false, true, false>
        <<<dim3(Mseg / 128, kDFF / 128), 256, 0, stream>>>(
            h, kD, w_f1, kD, xz, kDFF, kD, ff1_b, Mseg, r0);
    gemm_mfma<0, true, true, false, false, false, true>
        <<<dim3(Mseg / 128, kD / 128), 256, 0, stream>>>(
            xz, kDFF, w_f2, kDFF, out, kD, kDFF, ff2_b, Mseg, r0);
  }
}

// Round 6
// 1539.659 us; speedup vs baseline: 4.5793x; 1.0712x over previous
//
#include <hip/hip_runtime.h>
#include <cmath>

// ---------------------------------------------------------------------------
// BiDirectionalAddFFBlock: LN -> mamba(fwd)+mamba(rev) -> gelu residual ->
// LN -> FFN.  B=4, L=2048, D=1024, di=2048, ds=16, dt_rank=64, DFF=4096.
// Round 6: GEMM LDS fragment reads had 8-way bank conflicts (2.5e7/dispatch,
// ~40us/CU of replay).  XOR-swizzled LDS tile: staging permutes per-lane
// SOURCE col-block ((lane&7)^srow) so physical slot (r,p) holds logical
// (r, p^(r&7)); fragment reads XOR their col-block with l15&7.  Any 8
// sequential lanes now cover all 32 banks exactly once.
// ---------------------------------------------------------------------------

namespace {

using u16 = unsigned short;
using uint = unsigned int;

constexpr int kB = 4;
constexpr int kL = 2048;
constexpr int kD = 1024;
constexpr int kDI = 2048;
constexpr int kDFF = 4096;
constexpr int kDS = 16;
constexpr int kDtRank = 64;
constexpr int kNPad = 128;       // x_proj N=96 padded to 128
constexpr int kM = kB * kL;      // 8192 rows
constexpr int kNCH = 16;         // scan chunks per segment

typedef short bf16x8 __attribute__((ext_vector_type(8)));
typedef float f32x4  __attribute__((ext_vector_type(4)));

__device__ __forceinline__ float bf2f(u16 u) {
  union { unsigned int i; float f; } c; c.i = ((unsigned int)u) << 16; return c.f;
}
__device__ __forceinline__ u16 f2bf(float f) {  // round-to-nearest-even
  union { float f; unsigned int i; } c; c.f = f;
  return (u16)((c.i + 0x7FFFu + ((c.i >> 16) & 1u)) >> 16);
}
__device__ __forceinline__ float geluf(float v) {
  return 0.5f * v * (1.f + erff(v * 0.70710678118654752f));
}
__device__ __forceinline__ float softplusf(float v) {
  return (v > 0.f) ? (v + log1pf(__expf(-v))) : log1pf(__expf(v));
}
__device__ __forceinline__ float siluf(float v) {
  return v / (1.f + __expf(-v));
}

// async 16B global -> LDS (dest = wave-uniform lds base + lane*16)
__device__ __forceinline__ void async16(const u16* g, u16* l) {
  __builtin_amdgcn_global_load_lds(
      (const __attribute__((address_space(1))) uint*)g,
      (__attribute__((address_space(3))) uint*)l, 16, 0, 0);
}

// ---------------------------------------------------------------------------
// LayerNorm fp32 row (1024) -> bf16.  One block per row.
// ---------------------------------------------------------------------------
__global__ __launch_bounds__(256) void ln_kernel(
    const float* __restrict__ x, const float* __restrict__ g,
    const float* __restrict__ b, u16* __restrict__ out) {
  const int row = blockIdx.x;
  const int tid = threadIdx.x;
  const float4 v = ((const float4*)(x + (size_t)row * kD))[tid];
  float s  = v.x + v.y + v.z + v.w;
  float ss = v.x * v.x + v.y * v.y + v.z * v.z + v.w * v.w;
  #pragma unroll
  for (int off = 32; off; off >>= 1) {
    s  += __shfl_xor(s, off);
    ss += __shfl_xor(ss, off);
  }
  __shared__ float ls[4], lss[4];
  const int wid = tid >> 6;
  if ((tid & 63) == 0) { ls[wid] = s; lss[wid] = ss; }
  __syncthreads();
  s  = ls[0] + ls[1] + ls[2] + ls[3];
  ss = lss[0] + lss[1] + lss[2] + lss[3];
  const float mu  = s * (1.f / kD);
  const float inv = rsqrtf(ss * (1.f / kD) - mu * mu + 1e-5f);
  const float4 gg = ((const float4*)g)[tid];
  const float4 bb = ((const float4*)b)[tid];
  ushort4 o;
  o.x = f2bf((v.x - mu) * inv * gg.x + bb.x);
  o.y = f2bf((v.y - mu) * inv * gg.y + bb.y);
  o.z = f2bf((v.z - mu) * inv * gg.z + bb.z);
  o.w = f2bf((v.w - mu) * inv * gg.w + bb.w);
  ((ushort4*)(out + (size_t)row * kD))[tid] = o;
}

// fp32 -> bf16 convert, count divisible by 1024
__global__ __launch_bounds__(256) void cvt_kernel(
    const float* __restrict__ s, u16* __restrict__ d) {
  const int i = blockIdx.x * 256 + threadIdx.x;
  const float4 v = ((const float4*)s)[i];
  ushort4 o = { f2bf(v.x), f2bf(v.y), f2bf(v.z), f2bf(v.w) };
  ((ushort4*)d)[i] = o;
}

// xproj_w [96,2048] fp32 -> [128,2048] bf16 zero-padded
__global__ __launch_bounds__(256) void cvt_xproj_kernel(
    const float* __restrict__ s, u16* __restrict__ d) {
  const int i = blockIdx.x * 256 + threadIdx.x;  // over 128*2048/4
  const int r = (i * 4) / kDI;
  ushort4 o = {0, 0, 0, 0};
  if (r < kDtRank + 2 * kDS) {
    const float4 v = ((const float4*)s)[i];
    o.x = f2bf(v.x); o.y = f2bf(v.y); o.z = f2bf(v.z); o.w = f2bf(v.w);
  }
  ((ushort4*)d)[i] = o;
}

// ---------------------------------------------------------------------------
// bf16 MFMA GEMM: C[M,N] = A[M,K] * W[N,K]^T  (+bias)(+act)(+=C)
// 128x128 tile, BK=64, 4 waves (2x2), each 64x64 via 16x16x32 MFMA.
// Async global_load_lds width=16 into XOR-swizzled [128][64] LDS:
//   staging lane loads global col-block (lane&7)^srow  ->  physical (r,p)
//   holds logical (r, p^(r&7));  fragment read col-block ^= (l15&7).
// AMAP/CMAP: segment-compact row mapping (REV flips L within batch).
// ---------------------------------------------------------------------------
template <int ACT, bool BIAS, bool ACC, bool OUTBF, bool REV, bool AMAP,
          bool CMAP>
__global__ __launch_bounds__(256) void gemm_mfma(
    const u16* __restrict__ A, int lda,
    const u16* __restrict__ W, int ldw,
    void* __restrict__ Cp, int ldc, int K,
    const float* __restrict__ bias, int seg_len, int row_off) {
  __shared__ __align__(16) u16 As[128][64];
  __shared__ __align__(16) u16 Ws[128][64];
  const int tid  = threadIdx.x;
  const int bm   = blockIdx.x * 128;
  const int bn   = blockIdx.y * 128;
  const int lane = tid & 63;
  const int wv   = tid >> 6;
  const int wm   = (wv >> 1) * 64;
  const int wn   = (wv & 1) * 64;
  const int l15  = lane & 15;
  const int quad = lane >> 4;
  const int srow = lane >> 3;                  // 0..7 within 8-row strip
  const int swz  = ((lane & 7) ^ srow) * 8;    // swizzled source u16 col
  const int jx   = (l15 & 7) * 16;             // fragment byte-offset XOR mask

  int ab = 0, all0 = bm;
  if (AMAP || CMAP) {
    ab = bm / seg_len;
    all0 = bm - ab * seg_len;
  }

  // per-strip A global rows (strip it covers rows it*32 + wv*8 + srow)
  int arowv[4];
  #pragma unroll
  for (int it = 0; it < 4; it++) {
    const int rl = it * 32 + wv * 8 + srow;
    if (AMAP) {
      arowv[it] = REV ? (ab * kL + kL - 1 - row_off - all0 - rl)
                      : (ab * kL + row_off + all0 + rl);
    } else {
      arowv[it] = bm + rl;
    }
  }

  f32x4 acc[4][4];
  #pragma unroll
  for (int i = 0; i < 4; i++)
    #pragma unroll
    for (int j = 0; j < 4; j++) acc[i][j] = (f32x4){0.f, 0.f, 0.f, 0.f};

  for (int k0 = 0; k0 < K; k0 += 64) {
    #pragma unroll
    for (int it = 0; it < 4; it++) {
      const int rl = it * 32 + wv * 8 + srow;
      async16(A + (size_t)arowv[it] * lda + k0 + swz, &As[it * 32 + wv * 8][0]);
      async16(W + (size_t)(bn + rl) * ldw + k0 + swz, &Ws[it * 32 + wv * 8][0]);
    }
    __syncthreads();
    #pragma unroll
    for (int ks = 0; ks < 64; ks += 32) {
      const int cb = ((ks >> 3) + quad) * 16;  // logical col-block byte offset
      bf16x8 af[4], wf[4];
      #pragma unroll
      for (int i = 0; i < 4; i++)
        af[i] = *(const bf16x8*)((const char*)&As[wm + i * 16 + l15][0] +
                                 (cb ^ jx));
      #pragma unroll
      for (int j = 0; j < 4; j++)
        wf[j] = *(const bf16x8*)((const char*)&Ws[wn + j * 16 + l15][0] +
                                 (cb ^ jx));
      #pragma unroll
      for (int i = 0; i < 4; i++)
        #pragma unroll
        for (int j = 0; j < 4; j++)
          acc[i][j] = __builtin_amdgcn_mfma_f32_16x16x32_bf16(
              af[i], wf[j], acc[i][j], 0, 0, 0);
    }
    __syncthreads();
  }

  #pragma unroll
  for (int i = 0; i < 4; i++) {
    #pragma unroll
    for (int j = 0; j < 4; j++) {
      const int col = bn + wn + j * 16 + l15;
      #pragma unroll
      for (int r = 0; r < 4; r++) {
        const int rl2 = wm + i * 16 + quad * 4 + r;
        const int crow = CMAP ? (ab * kL + row_off + all0 + rl2) : (bm + rl2);
        float v = acc[i][j][r];
        if (BIAS) v += bias[col];
        if (ACT == 1) v = softplusf(v);
        if (ACT == 2) v = geluf(v);
        if (OUTBF) {
          ((u16*)Cp)[(size_t)crow * ldc + col] = f2bf(v);
        } else {
          float* p = (float*)Cp + (size_t)crow * ldc + col;
          if (ACC) *p = *p + v; else *p = v;
        }
      }
    }
  }
}

// ---------------------------------------------------------------------------
// Causal depthwise conv (k=4) + bias + silu on one segment (compact rows).
// ---------------------------------------------------------------------------
__global__ __launch_bounds__(256) void conv_silu_kernel(
    const u16* __restrict__ xz, const float* __restrict__ w,
    const float* __restrict__ cb, u16* __restrict__ xs,
    const u16* __restrict__ tail_in, u16* __restrict__ tail_out,
    int seg_len, int row_off) {
  const int t = blockIdx.x * 256 + threadIdx.x;  // Mseg*kDI threads
  const int c = t & (kDI - 1);
  const int r = t >> 11;              // compact row
  const int b = r / seg_len;
  const int ll = r - b * seg_len;
  const int tpos = row_off + ll;      // processing-order position in [0,L)

  const float xv0 = bf2f(xz[(size_t)r * (2 * kDI) + c]);
  float acc = cb[c] + w[c * 4 + 3] * xv0;
  #pragma unroll
  for (int j = 1; j <= 3; j++) {
    if (tpos - j >= 0) {
      float xp;
      if (ll - j >= 0) {
        xp = bf2f(xz[(size_t)(r - j) * (2 * kDI) + c]);
      } else {
        xp = bf2f(tail_in[(b * 3 + (3 + ll - j)) * kDI + c]);
      }
      acc += w[c * 4 + 3 - j] * xp;
    }
  }
  xs[(size_t)r * kDI + c] = f2bf(siluf(acc));
  if (ll >= seg_len - 3) {
    tail_out[(b * 3 + (ll - (seg_len - 3))) * kDI + c] = f2bf(xv0);
  }
}

// ---------------------------------------------------------------------------
// Scan phase A: per (b, c, chunk), 16 states in registers, no cross-lane.
// ---------------------------------------------------------------------------
__global__ __launch_bounds__(256) void scan_phaseA(
    const u16* __restrict__ dt, const u16* __restrict__ xs,
    const u16* __restrict__ dbl, const float* __restrict__ Alog,
    float* __restrict__ Pbuf, float* __restrict__ Hbuf,
    int Lseg, int Lc) {
  __shared__ float Bls[128][16];
  const int tid = threadIdx.x;
  const int c = blockIdx.x * 256 + tid;
  const int k = blockIdx.y;
  const int b = blockIdx.z;
  const int base = b * Lseg + k * Lc;
  for (int idx = tid; idx < Lc * 16; idx += 256) {
    const int r = idx >> 4, j = idx & 15;
    Bls[r][j] = bf2f(dbl[(size_t)(base + r) * kNPad + kDtRank + j]);
  }
  __syncthreads();
  float Ac[16], h[16], P[16];
  #pragma unroll
  for (int s = 0; s < 16; s++) {
    Ac[s] = -__expf(Alog[c * kDS + s]);
    h[s] = 0.f;
    P[s] = 1.f;
  }
  for (int r = 0; r < Lc; r++) {
    const size_t row = (size_t)(base + r);
    const float dtv = bf2f(dt[row * kDI + c]);
    const float dtx = dtv * bf2f(xs[row * kDI + c]);
    const float4* Brow = (const float4*)Bls[r];
    #pragma unroll
    for (int s4 = 0; s4 < 4; s4++) {
      const float4 Bv = Brow[s4];
      const float bb[4] = {Bv.x, Bv.y, Bv.z, Bv.w};
      #pragma unroll
      for (int q = 0; q < 4; q++) {
        const int s = s4 * 4 + q;
        const float dA = __expf(dtv * Ac[s]);
        h[s] = dA * h[s] + dtx * bb[q];
        P[s] *= dA;
      }
    }
  }
  const size_t o = (((size_t)b * kNCH + k) * kDI + c) * 16;
  #pragma unroll
  for (int s4 = 0; s4 < 4; s4++) {
    *(float4*)&Pbuf[o + s4 * 4] =
        make_float4(P[s4 * 4], P[s4 * 4 + 1], P[s4 * 4 + 2], P[s4 * 4 + 3]);
    *(float4*)&Hbuf[o + s4 * 4] =
        make_float4(h[s4 * 4], h[s4 * 4 + 1], h[s4 * 4 + 2], h[s4 * 4 + 3]);
  }
}

// ---------------------------------------------------------------------------
// Scan phase B: stitch chunks; h_in per chunk written over Pbuf.
// ---------------------------------------------------------------------------
__global__ __launch_bounds__(256) void scan_phaseB(
    float* __restrict__ Pbuf, const float* __restrict__ Hbuf,
    float* __restrict__ hstate, int first) {
  const int t = blockIdx.x * 256 + threadIdx.x;  // B*di*16
  const int s = t & 15;
  const int c = (t >> 4) & (kDI - 1);
  const int b = t >> 15;
  float cur = first ? 0.f : hstate[t];
  for (int k = 0; k < kNCH; k++) {
    const size_t idx = (((size_t)b * kNCH + k) * kDI + c) * 16 + s;
    const float p = Pbuf[idx];
    const float hl = Hbuf[idx];
    Pbuf[idx] = cur;
    cur = p * cur + hl;
  }
  hstate[t] = cur;
}

// ---------------------------------------------------------------------------
// Scan phase C: re-run chunk with true h_in, y = C.h + D*x, *silu(z) -> xs.
// ---------------------------------------------------------------------------
__global__ __launch_bounds__(256) void scan_phaseC(
    const u16* __restrict__ dt, u16* __restrict__ xs,
    const u16* __restrict__ dbl, const u16* __restrict__ xz,
    const float* __restrict__ Alog, const float* __restrict__ Dp,
    const float* __restrict__ Pbuf, int Lseg, int Lc) {
  __shared__ float BC[128][32];  // [r][0:16]=B, [r][16:32]=C
  const int tid = threadIdx.x;
  const int c = blockIdx.x * 256 + tid;
  const int k = blockIdx.y;
  const int b = blockIdx.z;
  const int base = b * Lseg + k * Lc;
  for (int idx = tid; idx < Lc * 32; idx += 256) {
    const int r = idx >> 5, j = idx & 31;
    BC[r][j] = bf2f(dbl[(size_t)(base + r) * kNPad + kDtRank + j]);
  }
  __syncthreads();
  float Ac[16], h[16];
  const size_t o = (((size_t)b * kNCH + k) * kDI + c) * 16;
  #pragma unroll
  for (int s4 = 0; s4 < 4; s4++) {
    const float4 hv = *(const float4*)&Pbuf[o + s4 * 4];
    h[s4 * 4 + 0] = hv.x; h[s4 * 4 + 1] = hv.y;
    h[s4 * 4 + 2] = hv.z; h[s4 * 4 + 3] = hv.w;
  }
  #pragma unroll
  for (int s = 0; s < 16; s++) Ac[s] = -__expf(Alog[c * kDS + s]);
  const float Dv = Dp[c];
  for (int r = 0; r < Lc; r++) {
    const size_t row = (size_t)(base + r);
    const float dtv = bf2f(dt[row * kDI + c]);
    const float xv = bf2f(xs[row * kDI + c]);
    const float dtx = dtv * xv;
    float y = 0.f;
    const float4* Brow = (const float4*)BC[r];
    const float4* Crow = (const float4*)&BC[r][16];
    #pragma unroll
    for (int s4 = 0; s4 < 4; s4++) {
      const float4 Bv = Brow[s4];
      const float4 Cv = Crow[s4];
      const float bb[4] = {Bv.x, Bv.y, Bv.z, Bv.w};
      const float cc[4] = {Cv.x, Cv.y, Cv.z, Cv.w};
      #pragma unroll
      for (int q = 0; q < 4; q++) {
        const int s = s4 * 4 + q;
        const float dA = __expf(dtv * Ac[s]);
        h[s] = dA * h[s] + dtx * bb[q];
        y += h[s] * cc[q];
      }
    }
    const float z = bf2f(xz[row * (2 * kDI) + kDI + c]);
    xs[row * kDI + c] = f2bf((y + Dv * xv) * siluf(z));
  }
}

// out = x + gelu(out + x)  in place (out currently holds fwd+bwd, f32)
__global__ __launch_bounds__(256) void combine_kernel(
    const float* __restrict__ x, float* __restrict__ out) {
  const size_t i = (size_t)blockIdx.x * 256 + threadIdx.x;  // M*D/4
  const float4 xv = ((const float4*)x)[i];
  const float4 bv = ((const float4*)out)[i];
  float4 o;
  o.x = xv.x + geluf(bv.x + xv.x);
  o.y = xv.y + geluf(bv.y + xv.y);
  o.z = xv.z + geluf(bv.z + xv.z);
  o.w = xv.w + geluf(bv.w + xv.w);
  ((float4*)out)[i] = o;
}

}  // namespace

extern "C" void kernel_launch(void* const* d_in, const int* in_sizes, int n_in,
                              void* d_out, int out_size, void* d_ws,
                              size_t ws_size, hipStream_t stream) {
  const float* x = (const float*)d_in[0];
  const float* in_w[2]    = {(const float*)d_in[1],  (const float*)d_in[10]};
  const float* conv_w[2]  = {(const float*)d_in[2],  (const float*)d_in[11]};
  const float* conv_b[2]  = {(const float*)d_in[3],  (const float*)d_in[12]};
  const float* xproj_w[2] = {(const float*)d_in[4],  (const float*)d_in[13]};
  const float* dt_w[2]    = {(const float*)d_in[5],  (const float*)d_in[14]};
  const float* dt_b[2]    = {(const float*)d_in[6],  (const float*)d_in[15]};
  const float* Alog[2]    = {(const float*)d_in[7],  (const float*)d_in[16]};
  const float* Dp[2]      = {(const float*)d_in[8],  (const float*)d_in[17]};
  const float* out_w[2]   = {(const float*)d_in[9],  (const float*)d_in[18]};
  const float* norm_g = (const float*)d_in[19];
  const float* norm_b = (const float*)d_in[20];
  const float* ffn_g  = (const float*)d_in[21];
  const float* ffn_b  = (const float*)d_in[22];
  const float* ff1_w  = (const float*)d_in[23];
  const float* ff1_b  = (const float*)d_in[24];
  const float* ff2_w  = (const float*)d_in[25];
  const float* ff2_b  = (const float*)d_in[26];
  float* out = (float*)d_out;

  // --- adaptive workspace layout ---------------------------------------
  constexpr size_t kWCache =
      2 * ((size_t)4096 * kD + (size_t)kD * kDI + (size_t)kNPad * kDI +
           (size_t)kDI * kDtRank) * 2 +
      ((size_t)kDFF * kD + (size_t)kD * kDFF) * 2;  // bf16 weights
  auto need = [](int nseg) -> size_t {
    const size_t mseg = (size_t)kM / nseg;
    size_t sz = kWCache + 4096;
    sz += (size_t)kM * kD * 2;            // h bf16
    sz += mseg * 4096 * 2;                // xz bf16 (aliases FFN hidden)
    sz += mseg * 2048 * 2;                // xs bf16
    sz += mseg * 128 * 2;                 // dbl bf16
    sz += mseg * 2048 * 2;                // dt bf16
    sz += 2 * (size_t)kB * kNCH * kDI * kDS * 4;  // Pbuf + Hbuf
    sz += (size_t)kB * kDI * kDS * 4;     // hstate
    sz += 2 * (size_t)kB * 3 * kDI * 2;   // conv tails
    sz += 32 * 256;                       // alignment slack
    return sz;
  };
  int nseg = 1;
  while (nseg <= 16 && need(nseg) > ws_size) nseg *= 2;
  if (nseg > 16) return;  // clean fail
  const int Lseg = kL / nseg;
  const int Mseg = kM / nseg;
  const int Lc = Lseg / kNCH;

  char* base = (char*)d_ws;
  size_t off = 0;
  auto alloc = [&](size_t bytes) {
    char* p = base + off;
    off = (off + bytes + 255) & ~(size_t)255;
    return p;
  };
  // bf16 weight cache
  u16* w_in[2], *w_out[2], *w_xp[2], *w_dt[2];
  for (int m = 0; m < 2; m++) {
    w_in[m]  = (u16*)alloc((size_t)4096 * kD * 2);
    w_out[m] = (u16*)alloc((size_t)kD * kDI * 2);
    w_xp[m]  = (u16*)alloc((size_t)kNPad * kDI * 2);
    w_dt[m]  = (u16*)alloc((size_t)kDI * kDtRank * 2);
  }
  u16* w_f1 = (u16*)alloc((size_t)kDFF * kD * 2);
  u16* w_f2 = (u16*)alloc((size_t)kD * kDFF * 2);
  // activations
  u16*   h      = (u16*)alloc((size_t)kM * kD * 2);
  u16*   xz     = (u16*)alloc((size_t)Mseg * 4096 * 2);
  u16*   xs     = (u16*)alloc((size_t)Mseg * 2048 * 2);
  u16*   dbl    = (u16*)alloc((size_t)Mseg * 128 * 2);
  u16*   dtb    = (u16*)alloc((size_t)Mseg * 2048 * 2);
  float* Pbuf   = (float*)alloc((size_t)kB * kNCH * kDI * kDS * 4);
  float* Hbuf   = (float*)alloc((size_t)kB * kNCH * kDI * kDS * 4);
  float* hstate = (float*)alloc((size_t)kB * kDI * kDS * 4);
  u16*   tail0  = (u16*)alloc((size_t)kB * 3 * kDI * 2);
  u16*   tail1  = (u16*)alloc((size_t)kB * 3 * kDI * 2);

  // weight conversion (once per call)
  for (int m = 0; m < 2; m++) {
    cvt_kernel<<<(4096 * kD) / 1024, 256, 0, stream>>>(in_w[m], w_in[m]);
    cvt_kernel<<<(kD * kDI) / 1024, 256, 0, stream>>>(out_w[m], w_out[m]);
    cvt_xproj_kernel<<<(kNPad * kDI) / 1024, 256, 0, stream>>>(xproj_w[m],
                                                               w_xp[m]);
    cvt_kernel<<<(kDI * kDtRank) / 1024, 256, 0, stream>>>(dt_w[m], w_dt[m]);
  }
  cvt_kernel<<<(kDFF * kD) / 1024, 256, 0, stream>>>(ff1_w, w_f1);
  cvt_kernel<<<(kD * kDFF) / 1024, 256, 0, stream>>>(ff2_w, w_f2);

  // LN(x) -> h (bf16)
  ln_kernel<<<kM, 256, 0, stream>>>(x, norm_g, norm_b, h);

  for (int m = 0; m < 2; m++) {
    for (int s = 0; s < nseg; s++) {
      const int l0 = s * Lseg;
      u16* tin  = (s & 1) ? tail0 : tail1;
      u16* tout = (s & 1) ? tail1 : tail0;
      // in_proj: h rows (REV for m=1) x in_w[4096,1024]^T -> xz [Mseg,4096]
      if (m == 0)
        gemm_mfma<0, false, false, true, false, true, false>
            <<<dim3(Mseg / 128, 4096 / 128), 256, 0, stream>>>(
                h, kD, w_in[m], kD, xz, 4096, kD, nullptr, Lseg, l0);
      else
        gemm_mfma<0, false, false, true, true, true, false>
            <<<dim3(Mseg / 128, 4096 / 128), 256, 0, stream>>>(
                h, kD, w_in[m], kD, xz, 4096, kD, nullptr, Lseg, l0);
      // causal depthwise conv + silu -> xs
      conv_silu_kernel<<<(Mseg * kDI) / 256, 256, 0, stream>>>(
          xz, conv_w[m], conv_b[m], xs, tin, tout, Lseg, l0);
      // x_proj: xs x xproj[128(pad),2048]^T -> dbl bf16 [Mseg,128]
      gemm_mfma<0, false, false, true, false, false, false>
          <<<dim3(Mseg / 128, 1), 256, 0, stream>>>(
              xs, kDI, w_xp[m], kDI, dbl, kNPad, kDI, nullptr, Lseg, l0);
      // dt_proj + softplus: dbl[:, :64] x dt_w[2048,64]^T -> dt bf16
      gemm_mfma<1, true, false, true, false, false, false>
          <<<dim3(Mseg / 128, kDI / 128), 256, 0, stream>>>(
              dbl, kNPad, w_dt[m], kDtRank, dtb, kDI, kDtRank, dt_b[m],
              Lseg, l0);
      // chunked scan: A (local), B (stitch), C (emit y into xs)
      scan_phaseA<<<dim3(kDI / 256, kNCH, kB), 256, 0, stream>>>(
          dtb, xs, dbl, Alog[m], Pbuf, Hbuf, Lseg, Lc);
      scan_phaseB<<<(kB * kDI * kDS) / 256, 256, 0, stream>>>(
          Pbuf, Hbuf, hstate, (s == 0) ? 1 : 0);
      scan_phaseC<<<dim3(kDI / 256, kNCH, kB), 256, 0, stream>>>(
          dtb, xs, dbl, xz, Alog[m], Dp[m], Pbuf, Lseg, Lc);
      // out_proj -> d_out rows (f32); m=1 accumulates
      if (m == 0)
        gemm_mfma<0, false, false, false, false, false, true>
            <<<dim3(Mseg / 128, kD / 128), 256, 0, stream>>>(
                xs, kDI, w_out[m], kDI, out, kD, kDI, nullptr, Lseg, l0);
      else
        gemm_mfma<0, false, true, false, false, false, true>
            <<<dim3(Mseg / 128, kD / 128), 256, 0, stream>>>(
                xs, kDI, w_out[m], kDI, out, kD, kDI, nullptr, Lseg, l0);
    }
  }

  // x2 = x + gelu(fwd + bwd + x), in place on d_out
  combine_kernel<<<(kM * kD) / 1024, 256, 0, stream>>>(x, out);

  // FFN: LN(x2) -> h ; per M-segment: hidden = gelu(h@ff1^T+b1) (alias xz);
  // out += hidden@ff2^T + b2
  ln_kernel<<<kM, 256, 0, stream>>>(out, ffn_g, ffn_b, h);
  for (int s = 0; s < nseg; s++) {
    const int r0 = s * Mseg;
    gemm_mfma<2, true, false, true, false, true, false>
        <<<dim3(Mseg / 128, kDFF / 128), 256, 0, stream>>>(
            h, kD, w_f1, kD, xz, kDFF, kD, ff1_b, Mseg, r0);
    gemm_mfma<0, true, true, false, false, false, true>
        <<<dim3(Mseg / 128, kD / 128), 256, 0, stream>>>(
            xz, kDFF, w_f2, kDFF, out, kD, kDFF, ff2_b, Mseg, r0);
  }
}